// Round 8
// baseline (539.019 us; speedup 1.0000x reference)
//
#include <hip/hip_runtime.h>
#include <hip/hip_bf16.h>
#include <math.h>

// ---------------------------------------------------------------------------
// GAT 3-layer forward.
// R8 changes:
//  - agg4: feat-row gathers issued BEFORE the softmax (addresses depend only
//    on csr, not alpha). csr loaded once coalesced (lane=edge), src broadcast
//    via __shfl; up to PF=24 edges x 2 dwords prefetched into registers ->
//    gather latency overlaps softmax VALU. s_src LDS dropped in fast path.
//  - layer-2: el/er + bf16 cast fused into gemm_kernel epilogue
//    (elr<1,16> dispatch and fp32 feat round-trip deleted).
// ---------------------------------------------------------------------------

#define NEG_SLOPE 0.2f

typedef __attribute__((ext_vector_type(8))) short v8s;   // 8 bf16 in 4 VGPRs
typedef __attribute__((ext_vector_type(4))) float f32x4;

// ---------------- CSR build ----------------

__global__ __launch_bounds__(256) void count_deg(const int* __restrict__ dst,
                                                 int* __restrict__ deg, int E) {
    int e = blockIdx.x * 256 + threadIdx.x;
    if (e < E) atomicAdd(&deg[dst[e]], 1);
}

__global__ __launch_bounds__(256) void scan_chunk(int* __restrict__ off,
                                                  int* __restrict__ chunkSum, int N) {
    __shared__ int sdata[256];
    int tid = threadIdx.x;
    int base = blockIdx.x * 2048 + tid * 8;
    int v[8];
    int tsum = 0;
#pragma unroll
    for (int j = 0; j < 8; ++j) {
        int idx = base + j;
        v[j] = (idx < N) ? off[idx] : 0;
        tsum += v[j];
    }
    sdata[tid] = tsum;
    __syncthreads();
    for (int o = 1; o < 256; o <<= 1) {
        int t = (tid >= o) ? sdata[tid - o] : 0;
        __syncthreads();
        sdata[tid] += t;
        __syncthreads();
    }
    int run = sdata[tid] - tsum;
#pragma unroll
    for (int j = 0; j < 8; ++j) {
        int idx = base + j;
        if (idx < N) off[idx] = run;
        run += v[j];
    }
    if (tid == 255) chunkSum[blockIdx.x] = sdata[255];
}

__global__ void scan_tail(const int* __restrict__ chunkSum, int* __restrict__ chunkOff,
                          int nchunks, int* __restrict__ off, int N, int E) {
    if (threadIdx.x == 0 && blockIdx.x == 0) {
        int run = 0;
        for (int c = 0; c < nchunks; ++c) { chunkOff[c] = run; run += chunkSum[c]; }
        off[N] = E;
    }
}

__global__ __launch_bounds__(256) void add_chunk_off(int* __restrict__ off,
                                                     int* __restrict__ cursor,
                                                     const int* __restrict__ chunkOff, int N) {
    int i = blockIdx.x * 256 + threadIdx.x;
    if (i < N) {
        int v = off[i] + chunkOff[i >> 11];
        off[i] = v;
        cursor[i] = v;
    }
}

__global__ __launch_bounds__(256) void scatter_edges(const int* __restrict__ src,
                                                     const int* __restrict__ dst,
                                                     int* __restrict__ cursor,
                                                     int* __restrict__ csr, int E) {
    int e = blockIdx.x * 256 + threadIdx.x;
    if (e < E) {
        int d = dst[e];
        int pos = atomicAdd(&cursor[d], 1);
        csr[pos] = src[e];
    }
}

// ---------------- bf16 split helpers ----------------

__device__ __forceinline__ unsigned short bf16_rne(float x) {
    unsigned int u = __float_as_uint(x);
    return (unsigned short)((u + 0x7fffu + ((u >> 16) & 1u)) >> 16);
}

__device__ __forceinline__ void split2(float v, unsigned short& h, unsigned short& l) {
    unsigned int u = __float_as_uint(v);
    unsigned int uh = (u + 0x7fffu + ((u >> 16) & 1u)) & 0xffff0000u;
    h = (unsigned short)(uh >> 16);
    l = bf16_rne(v - __uint_as_float(uh));
}

// W prep: read W[F][K] fp32, write Wt_hi/Wt_lo as [K][F] bf16 (transposed).
__global__ __launch_bounds__(256) void wsplit(const float* __restrict__ W,
                                              unsigned short* __restrict__ thi,
                                              unsigned short* __restrict__ tlo,
                                              int F, int K) {
    int idx = blockIdx.x * 256 + threadIdx.x;
    if (idx >= F * K) return;
    int f = idx / K, k = idx % K;
    float v = W[idx];
    unsigned short h, l;
    split2(v, h, l);
    thi[k * F + f] = h;
    tlo[k * F + f] = l;
}

// A prep: fp32 stream -> hi/lo bf16 (no transpose). 4 elems/thread.
__global__ __launch_bounds__(256) void asplit(const float* __restrict__ A,
                                              unsigned short* __restrict__ hi,
                                              unsigned short* __restrict__ lo,
                                              int total4) {
    int i = blockIdx.x * 256 + threadIdx.x;
    if (i >= total4) return;
    float4 v = *(const float4*)&A[(size_t)i * 4];
    unsigned short h[4], l[4];
    split2(v.x, h[0], l[0]); split2(v.y, h[1], l[1]);
    split2(v.z, h[2], l[2]); split2(v.w, h[3], l[3]);
    *(ushort4*)&hi[(size_t)i * 4] = make_ushort4(h[0], h[1], h[2], h[3]);
    *(ushort4*)&lo[(size_t)i * 4] = make_ushort4(l[0], l[1], l[2], l[3]);
}

// ---------------- MFMA GEMM (pre-split A) fused with el/er ----------------

__global__ __launch_bounds__(256) void gemm_mfma(const unsigned short* __restrict__ Ahi,
                                                 const unsigned short* __restrict__ Alo,
                                                 const unsigned short* __restrict__ Bthi,
                                                 const unsigned short* __restrict__ Btlo,
                                                 unsigned short* __restrict__ featb,
                                                 float* __restrict__ el,
                                                 float* __restrict__ er,
                                                 const float* __restrict__ al,
                                                 const float* __restrict__ ar,
                                                 int N, int F, int K) {
    __shared__ unsigned short As[2][128][40];
    __shared__ unsigned short Bs[2][128][40];
    int tid = threadIdx.x;
    int lane = tid & 63, w = tid >> 6;
    int wr = (w >> 1) * 64, wc = (w & 1) * 64;
    int lr = lane & 15, lq = lane >> 4;
    int m0 = blockIdx.y * 128, n0 = blockIdx.x * 128;
    f32x4 acc[4][4] = {};

    for (int k0 = 0; k0 < F; k0 += 32) {
        __syncthreads();
#pragma unroll
        for (int i = 0; i < 4; ++i) {
            int c = i * 256 + tid;
            int s = c >> 9, r = (c >> 2) & 127, cc = c & 3;
            const unsigned short* Asrc = s ? Alo : Ahi;
            uint4 v = make_uint4(0u, 0u, 0u, 0u);
            int gr = m0 + r;
            if (gr < N) v = *(const uint4*)&Asrc[(size_t)gr * F + k0 + cc * 8];
            *(uint4*)&As[s][r][cc * 8] = v;
        }
#pragma unroll
        for (int i = 0; i < 4; ++i) {
            int c = i * 256 + tid;
            int s = c >> 9, r = (c >> 2) & 127, cc = c & 3;
            const unsigned short* B = s ? Btlo : Bthi;
            uint4 bv = *(const uint4*)&B[(size_t)(n0 + r) * F + k0 + cc * 8];
            *(uint4*)&Bs[s][r][cc * 8] = bv;
        }
        __syncthreads();

        v8s af[2][4], bf[2][4];
#pragma unroll
        for (int mt = 0; mt < 4; ++mt) {
            af[0][mt] = *(const v8s*)&As[0][wr + mt * 16 + lr][lq * 8];
            af[1][mt] = *(const v8s*)&As[1][wr + mt * 16 + lr][lq * 8];
        }
#pragma unroll
        for (int nt = 0; nt < 4; ++nt) {
            bf[0][nt] = *(const v8s*)&Bs[0][wc + nt * 16 + lr][lq * 8];
            bf[1][nt] = *(const v8s*)&Bs[1][wc + nt * 16 + lr][lq * 8];
        }
#pragma unroll
        for (int mt = 0; mt < 4; ++mt)
#pragma unroll
            for (int nt = 0; nt < 4; ++nt) {
                acc[mt][nt] = __builtin_amdgcn_mfma_f32_16x16x32_bf16(af[0][mt], bf[0][nt], acc[mt][nt], 0, 0, 0);
                acc[mt][nt] = __builtin_amdgcn_mfma_f32_16x16x32_bf16(af[0][mt], bf[1][nt], acc[mt][nt], 0, 0, 0);
                acc[mt][nt] = __builtin_amdgcn_mfma_f32_16x16x32_bf16(af[1][mt], bf[0][nt], acc[mt][nt], 0, 0, 0);
            }
    }

    // ---- fused epilogue ----
    int h = (n0 + wc) >> 6;  // head (D=64)
    float alw[4], arw[4];
#pragma unroll
    for (int nt = 0; nt < 4; ++nt) {
        int d = nt * 16 + lr;
        alw[nt] = al[h * 64 + d];
        arw[nt] = ar[h * 64 + d];
    }
#pragma unroll
    for (int mt = 0; mt < 4; ++mt) {
#pragma unroll
        for (int r = 0; r < 4; ++r) {
            float se = 0.f, sr = 0.f;
#pragma unroll
            for (int nt = 0; nt < 4; ++nt) {
                float v = acc[mt][nt][r];
                se += v * alw[nt];
                sr += v * arw[nt];
            }
#pragma unroll
            for (int o = 8; o >= 1; o >>= 1) {
                se += __shfl_xor(se, o);
                sr += __shfl_xor(sr, o);
            }
            int row = m0 + wr + mt * 16 + lq * 4 + r;
            if (lr == 0 && row < N) {
                el[(size_t)row * 4 + h] = se;
                er[(size_t)row * 4 + h] = sr;
            }
        }
    }
#pragma unroll
    for (int mt = 0; mt < 4; ++mt) {
#pragma unroll
        for (int nt = 0; nt < 4; ++nt) {
            int col = n0 + wc + nt * 16 + lr;
#pragma unroll
            for (int r = 0; r < 4; ++r) {
                int row = m0 + wr + mt * 16 + lq * 4 + r;
                if (row < N) featb[(size_t)row * K + col] = bf16_rne(acc[mt][nt][r]);
            }
        }
    }
}

// ---------------- fp32 GEMM (layer 2, K=16) fused with el/er + bf16 ------

__global__ __launch_bounds__(256) void gemm_kernel(const unsigned short* __restrict__ Ahi,
                                                   const unsigned short* __restrict__ Alo,
                                                   const float* __restrict__ W,
                                                   const float* __restrict__ al2,
                                                   const float* __restrict__ ar2,
                                                   float* __restrict__ el,
                                                   float* __restrict__ er,
                                                   unsigned short* __restrict__ featb,
                                                   int N, int F, int K) {
    __shared__ __align__(16) float As2[16][68];
    __shared__ __align__(16) float Ws2[16][64];
    int tid = threadIdx.x;
    int tx = tid & 15, ty = tid >> 4;
    int r0 = blockIdx.y * 64;
    int arow = tid >> 2, akq = tid & 3;
    int wk = tid >> 4, wcq = tid & 15;
    float acc[4][4] = {};

    for (int k0 = 0; k0 < F; k0 += 16) {
        float4 av = make_float4(0.f, 0.f, 0.f, 0.f);
        int gr = r0 + arow;
        if (gr < N) {
            size_t base = (size_t)gr * F + k0 + akq * 4;
            uint2 vh = *(const uint2*)&Ahi[base];
            uint2 vl = *(const uint2*)&Alo[base];
            av.x = __uint_as_float(vh.x << 16) + __uint_as_float(vl.x << 16);
            av.y = __uint_as_float(vh.x & 0xffff0000u) + __uint_as_float(vl.x & 0xffff0000u);
            av.z = __uint_as_float(vh.y << 16) + __uint_as_float(vl.y << 16);
            av.w = __uint_as_float(vh.y & 0xffff0000u) + __uint_as_float(vl.y & 0xffff0000u);
        }
        float4 wv = make_float4(0.f, 0.f, 0.f, 0.f);
        int gc = wcq * 4;
        if (gc < K) wv = *(const float4*)&W[(size_t)(k0 + wk) * K + gc];
        __syncthreads();
        As2[akq * 4 + 0][arow] = av.x;
        As2[akq * 4 + 1][arow] = av.y;
        As2[akq * 4 + 2][arow] = av.z;
        As2[akq * 4 + 3][arow] = av.w;
        *(float4*)&Ws2[wk][wcq * 4] = wv;
        __syncthreads();
#pragma unroll
        for (int k = 0; k < 16; ++k) {
            float4 a = *(const float4*)&As2[k][ty * 4];
            float4 wv2 = *(const float4*)&Ws2[k][tx * 4];
            acc[0][0] += a.x * wv2.x; acc[0][1] += a.x * wv2.y; acc[0][2] += a.x * wv2.z; acc[0][3] += a.x * wv2.w;
            acc[1][0] += a.y * wv2.x; acc[1][1] += a.y * wv2.y; acc[1][2] += a.y * wv2.z; acc[1][3] += a.y * wv2.w;
            acc[2][0] += a.z * wv2.x; acc[2][1] += a.z * wv2.y; acc[2][2] += a.z * wv2.z; acc[2][3] += a.z * wv2.w;
            acc[3][0] += a.w * wv2.x; acc[3][1] += a.w * wv2.y; acc[3][2] += a.w * wv2.z; acc[3][3] += a.w * wv2.w;
        }
    }
    // fused epilogue: el/er reduce across tx=0..3 (K=16) + bf16 store
    float alv[4] = {0.f, 0.f, 0.f, 0.f}, arv[4] = {0.f, 0.f, 0.f, 0.f};
    if (tx < 4) {
#pragma unroll
        for (int c = 0; c < 4; ++c) {
            alv[c] = al2[tx * 4 + c];
            arv[c] = ar2[tx * 4 + c];
        }
    }
#pragma unroll
    for (int i = 0; i < 4; ++i) {
        int gr = r0 + ty * 4 + i;
        float pe = 0.f, pr = 0.f;
        if (tx < 4) {
#pragma unroll
            for (int c = 0; c < 4; ++c) {
                pe += acc[i][c] * alv[c];
                pr += acc[i][c] * arv[c];
            }
        }
        pe += __shfl_xor(pe, 1); pr += __shfl_xor(pr, 1);
        pe += __shfl_xor(pe, 2); pr += __shfl_xor(pr, 2);
        if (tx == 0 && gr < N) {
            el[gr] = pe;
            er[gr] = pr;
        }
        if (tx < 4 && gr < N) {
            ushort4 o4 = make_ushort4(bf16_rne(acc[i][0]), bf16_rne(acc[i][1]),
                                      bf16_rne(acc[i][2]), bf16_rne(acc[i][3]));
            *(ushort4*)&featb[(size_t)gr * 16 + tx * 4] = o4;
        }
    }
}

// ---------------- agg for H=4, D=64: wave-per-node, prefetched ------------
// Fast path (deg<=64): csr loaded once (lane=edge), feat-row gathers for the
// first PF edges issued BEFORE the softmax (src broadcast via __shfl) so
// gather latency overlaps softmax VALU. Remaining edges batched U at a time.
// Slow path (deg>64) kept for correctness.

template <int CAP, int PF, int U>
__global__ __launch_bounds__(256) void agg4_kernel(const unsigned short* __restrict__ featb,
                                                   const float* __restrict__ el,
                                                   const float* __restrict__ er,
                                                   const float* __restrict__ bias,
                                                   const int* __restrict__ off,
                                                   const int* __restrict__ csr,
                                                   unsigned short* __restrict__ outhi,
                                                   unsigned short* __restrict__ outlo, int N) {
    __shared__ float s_alpha[4][4][CAP];  // [wave][head][edge]
    __shared__ int s_src[4][CAP];         // slow path only
    int w = threadIdx.x >> 6;
    int lane = threadIdx.x & 63;
    int n = blockIdx.x * 4 + w;
    if (n >= N) return;
    int begin = off[n];
    int deg = off[n + 1] - begin;
    const unsigned int* frow = (const unsigned int*)featb;
    int hsel = lane >> 5;  // 0: heads {0,2}; 1: heads {1,3}

    float m0 = -INFINITY, m1 = -INFINITY, m2 = -INFINITY, m3 = -INFINITY;
    float s0 = 0.f, s1 = 0.f, s2 = 0.f, s3 = 0.f;
    float a0 = 0.f, a1 = 0.f, a2 = 0.f, a3 = 0.f;
    float4 ern = *(const float4*)&er[(size_t)n * 4];

    if (deg <= 64) {
        bool act = lane < deg;
        int sreg = 0;
        if (act) sreg = csr[begin + lane];
        // el gather (needed by softmax) — issue first
        float4 e4 = make_float4(0.f, 0.f, 0.f, 0.f);
        if (act) e4 = *(const float4*)&el[(size_t)sreg * 4];
        // prefetch feat rows for first PF edges (independent of softmax)
        unsigned int f0[PF], f1[PF];
#pragma unroll
        for (int j = 0; j < PF; ++j) {
            if (j < deg) {  // wave-uniform branch
                int sj = __shfl(sreg, j);
                const unsigned int* rp = frow + (size_t)sj * 128;
                f0[j] = rp[lane];
                f1[j] = rp[64 + lane];
            } else {
                f0[j] = 0u;
                f1[j] = 0u;
            }
        }
        // softmax (overlaps the in-flight gathers)
        float e0 = -INFINITY, e1 = -INFINITY, e2 = -INFINITY, e3 = -INFINITY;
        if (act) {
            e0 = e4.x + ern.x; e1 = e4.y + ern.y; e2 = e4.z + ern.z; e3 = e4.w + ern.w;
            e0 = e0 > 0.f ? e0 : NEG_SLOPE * e0;
            e1 = e1 > 0.f ? e1 : NEG_SLOPE * e1;
            e2 = e2 > 0.f ? e2 : NEG_SLOPE * e2;
            e3 = e3 > 0.f ? e3 : NEG_SLOPE * e3;
        }
        m0 = e0; m1 = e1; m2 = e2; m3 = e3;
#pragma unroll
        for (int o = 32; o >= 1; o >>= 1) {
            m0 = fmaxf(m0, __shfl_xor(m0, o));
            m1 = fmaxf(m1, __shfl_xor(m1, o));
            m2 = fmaxf(m2, __shfl_xor(m2, o));
            m3 = fmaxf(m3, __shfl_xor(m3, o));
        }
        if (act) {
            s0 = __expf(e0 - m0); s1 = __expf(e1 - m1);
            s2 = __expf(e2 - m2); s3 = __expf(e3 - m3);
            s_alpha[w][0][lane] = s0;
            s_alpha[w][1][lane] = s1;
            s_alpha[w][2][lane] = s2;
            s_alpha[w][3][lane] = s3;
        }
#pragma unroll
        for (int o = 32; o >= 1; o >>= 1) {
            s0 += __shfl_xor(s0, o); s1 += __shfl_xor(s1, o);
            s2 += __shfl_xor(s2, o); s3 += __shfl_xor(s3, o);
        }
        // FMA over prefetched edges
        int mpf = deg < PF ? deg : PF;
#pragma unroll
        for (int j = 0; j < PF; ++j) {
            if (j < mpf) {  // wave-uniform
                float aA = s_alpha[w][hsel][j];
                float aB = s_alpha[w][2 + hsel][j];
                a0 += aA * __uint_as_float(f0[j] << 16);
                a1 += aA * __uint_as_float(f0[j] & 0xffff0000u);
                a2 += aB * __uint_as_float(f1[j] << 16);
                a3 += aB * __uint_as_float(f1[j] & 0xffff0000u);
            }
        }
        // remaining edges, batched U at a time (src via __shfl from sreg)
        for (int j = PF; j < deg; j += U) {
            unsigned int g0[U], g1[U];
            float aA[U], aB[U];
#pragma unroll
            for (int u = 0; u < U; ++u) {
                if (j + u < deg) {
                    int sj = __shfl(sreg, j + u);
                    const unsigned int* rp = frow + (size_t)sj * 128;
                    g0[u] = rp[lane];
                    g1[u] = rp[64 + lane];
                } else { g0[u] = 0u; g1[u] = 0u; }
            }
#pragma unroll
            for (int u = 0; u < U; ++u) {
                if (j + u < deg) {
                    aA[u] = s_alpha[w][hsel][j + u];
                    aB[u] = s_alpha[w][2 + hsel][j + u];
                } else { aA[u] = 0.f; aB[u] = 0.f; }
            }
#pragma unroll
            for (int u = 0; u < U; ++u) {
                a0 += aA[u] * __uint_as_float(g0[u] << 16);
                a1 += aA[u] * __uint_as_float(g0[u] & 0xffff0000u);
                a2 += aB[u] * __uint_as_float(g1[u] << 16);
                a3 += aB[u] * __uint_as_float(g1[u] & 0xffff0000u);
            }
        }
    } else {
        // ---- slow path (deg > 64): looped two-pass via LDS ----
        for (int i = lane; i < deg; i += 64) {
            int s = csr[begin + i];
            float4 e = *(const float4*)&el[(size_t)s * 4];
            float e0 = e.x + ern.x, e1 = e.y + ern.y, e2 = e.z + ern.z, e3 = e.w + ern.w;
            e0 = e0 > 0.f ? e0 : NEG_SLOPE * e0;
            e1 = e1 > 0.f ? e1 : NEG_SLOPE * e1;
            e2 = e2 > 0.f ? e2 : NEG_SLOPE * e2;
            e3 = e3 > 0.f ? e3 : NEG_SLOPE * e3;
            if (i < CAP) {
                s_src[w][i] = s;
                s_alpha[w][0][i] = e0; s_alpha[w][1][i] = e1;
                s_alpha[w][2][i] = e2; s_alpha[w][3][i] = e3;
            }
            m0 = fmaxf(m0, e0); m1 = fmaxf(m1, e1);
            m2 = fmaxf(m2, e2); m3 = fmaxf(m3, e3);
        }
#pragma unroll
        for (int o = 32; o >= 1; o >>= 1) {
            m0 = fmaxf(m0, __shfl_xor(m0, o));
            m1 = fmaxf(m1, __shfl_xor(m1, o));
            m2 = fmaxf(m2, __shfl_xor(m2, o));
            m3 = fmaxf(m3, __shfl_xor(m3, o));
        }
        for (int i = lane; i < deg; i += 64) {
            float e0, e1, e2, e3;
            if (i < CAP) {
                e0 = s_alpha[w][0][i]; e1 = s_alpha[w][1][i];
                e2 = s_alpha[w][2][i]; e3 = s_alpha[w][3][i];
            } else {
                int s = csr[begin + i];
                float4 e = *(const float4*)&el[(size_t)s * 4];
                e0 = e.x + ern.x; e1 = e.y + ern.y; e2 = e.z + ern.z; e3 = e.w + ern.w;
                e0 = e0 > 0.f ? e0 : NEG_SLOPE * e0;
                e1 = e1 > 0.f ? e1 : NEG_SLOPE * e1;
                e2 = e2 > 0.f ? e2 : NEG_SLOPE * e2;
                e3 = e3 > 0.f ? e3 : NEG_SLOPE * e3;
            }
            e0 = __expf(e0 - m0); e1 = __expf(e1 - m1);
            e2 = __expf(e2 - m2); e3 = __expf(e3 - m3);
            if (i < CAP) {
                s_alpha[w][0][i] = e0; s_alpha[w][1][i] = e1;
                s_alpha[w][2][i] = e2; s_alpha[w][3][i] = e3;
            }
            s0 += e0; s1 += e1; s2 += e2; s3 += e3;
        }
#pragma unroll
        for (int o = 32; o >= 1; o >>= 1) {
            s0 += __shfl_xor(s0, o); s1 += __shfl_xor(s1, o);
            s2 += __shfl_xor(s2, o); s3 += __shfl_xor(s3, o);
        }
        int dcap = deg < CAP ? deg : CAP;
        for (int j = 0; j < dcap; ++j) {
            int s = s_src[w][j];
            const unsigned int* rp = frow + (size_t)s * 128;
            unsigned int f0v = rp[lane], f1v = rp[64 + lane];
            float aA = s_alpha[w][hsel][j], aB = s_alpha[w][2 + hsel][j];
            a0 += aA * __uint_as_float(f0v << 16);
            a1 += aA * __uint_as_float(f0v & 0xffff0000u);
            a2 += aB * __uint_as_float(f1v << 16);
            a3 += aB * __uint_as_float(f1v & 0xffff0000u);
        }
        for (int i = CAP; i < deg; ++i) {
            int s = csr[begin + i];
            float4 e = *(const float4*)&el[(size_t)s * 4];
            float e0 = e.x + ern.x, e1 = e.y + ern.y, e2 = e.z + ern.z, e3 = e.w + ern.w;
            e0 = e0 > 0.f ? e0 : NEG_SLOPE * e0;
            e1 = e1 > 0.f ? e1 : NEG_SLOPE * e1;
            e2 = e2 > 0.f ? e2 : NEG_SLOPE * e2;
            e3 = e3 > 0.f ? e3 : NEG_SLOPE * e3;
            float x0 = __expf(e0 - m0), x1 = __expf(e1 - m1);
            float x2 = __expf(e2 - m2), x3 = __expf(e3 - m3);
            float aA = hsel ? x1 : x0, aB = hsel ? x3 : x2;
            const unsigned int* rp = frow + (size_t)s * 128;
            unsigned int f0v = rp[lane], f1v = rp[64 + lane];
            a0 += aA * __uint_as_float(f0v << 16);
            a1 += aA * __uint_as_float(f0v & 0xffff0000u);
            a2 += aB * __uint_as_float(f1v << 16);
            a3 += aB * __uint_as_float(f1v & 0xffff0000u);
        }
    }

    float inv0 = deg > 0 ? 1.f / s0 : 0.f;
    float inv1 = deg > 0 ? 1.f / s1 : 0.f;
    float inv2 = deg > 0 ? 1.f / s2 : 0.f;
    float inv3 = deg > 0 ? 1.f / s3 : 0.f;
    float invA = hsel ? inv1 : inv0;
    float invB = hsel ? inv3 : inv2;
    float o00 = a0 * invA + bias[2 * lane];
    float o01 = a1 * invA + bias[2 * lane + 1];
    float o10 = a2 * invB + bias[128 + 2 * lane];
    float o11 = a3 * invB + bias[128 + 2 * lane + 1];
    unsigned short h00, l00, h01, l01, h10, l10, h11, l11;
    split2(o00, h00, l00); split2(o01, h01, l01);
    split2(o10, h10, l10); split2(o11, h11, l11);
    unsigned int* ophi = (unsigned int*)outhi;
    unsigned int* oplo = (unsigned int*)outlo;
    ophi[(size_t)n * 128 + lane] = (unsigned int)h00 | ((unsigned int)h01 << 16);
    oplo[(size_t)n * 128 + lane] = (unsigned int)l00 | ((unsigned int)l01 << 16);
    ophi[(size_t)n * 128 + 64 + lane] = (unsigned int)h10 | ((unsigned int)h11 << 16);
    oplo[(size_t)n * 128 + 64 + lane] = (unsigned int)l10 | ((unsigned int)l11 << 16);
}

// ---------------- agg for H=1, D=16 (layer 2) ----------------

template <int H, int D, int CAP, int U>
__global__ __launch_bounds__(H * 64) void agg_kernel(const unsigned short* __restrict__ featb,
                                                     const float* __restrict__ el,
                                                     const float* __restrict__ er,
                                                     const float* __restrict__ bias,
                                                     const int* __restrict__ off,
                                                     const int* __restrict__ csr,
                                                     float* __restrict__ out, int N) {
    constexpr int HD = H * D;
    constexpr int L = D / 2;
    constexpr int ES = 64 / L;
    __shared__ float s_alpha[H][CAP];
    __shared__ int s_src[CAP];
    int n = blockIdx.x;
    int h = threadIdx.x >> 6;
    int lane = threadIdx.x & 63;
    int begin = off[n];
    int deg = off[n + 1] - begin;
    float er_nh = er[n * H + h];

    float m = -INFINITY;
    for (int i = lane; i < deg; i += 64) {
        int s = csr[begin + i];
        if (h == 0 && i < CAP) s_src[i] = s;
        float e = el[s * H + h] + er_nh;
        e = e > 0.f ? e : NEG_SLOPE * e;
        if (i < CAP) s_alpha[h][i] = e;
        m = fmaxf(m, e);
    }
#pragma unroll
    for (int o = 32; o >= 1; o >>= 1) m = fmaxf(m, __shfl_xor(m, o));

    float ss = 0.f;
    for (int i = lane; i < deg; i += 64) {
        float e;
        if (i < CAP) e = s_alpha[h][i];
        else {
            int s = csr[begin + i];
            e = el[s * H + h] + er_nh;
            e = e > 0.f ? e : NEG_SLOPE * e;
        }
        float x = __expf(e - m);
        ss += x;
        if (i < CAP) s_alpha[h][i] = x;
    }
#pragma unroll
    for (int o = 32; o >= 1; o >>= 1) ss += __shfl_xor(ss, o);
    float inv = (deg > 0) ? 1.f / ss : 0.f;

    __syncthreads();

    int slot = lane / L;
    int p = lane % L;
    int dcap = deg < CAP ? deg : CAP;
    const unsigned int* frow = (const unsigned int*)featb;
    size_t colOff = (size_t)(h * D) / 2 + p;
    float accx = 0.f, accy = 0.f;
    int j = slot;
    for (; j + (U - 1) * ES < dcap; j += U * ES) {
        float a[U];
        unsigned int f[U];
        int s[U];
#pragma unroll
        for (int u = 0; u < U; ++u) {
            int idx = j + u * ES;
            s[u] = s_src[idx];
            a[u] = s_alpha[h][idx];
        }
#pragma unroll
        for (int u = 0; u < U; ++u)
            f[u] = frow[(size_t)s[u] * (HD / 2) + colOff];
#pragma unroll
        for (int u = 0; u < U; ++u) {
            accx += a[u] * __uint_as_float(f[u] << 16);
            accy += a[u] * __uint_as_float(f[u] & 0xffff0000u);
        }
    }
    for (; j < dcap; j += ES) {
        float a = s_alpha[h][j];
        unsigned int f = frow[(size_t)s_src[j] * (HD / 2) + colOff];
        accx += a * __uint_as_float(f << 16);
        accy += a * __uint_as_float(f & 0xffff0000u);
    }
    for (int i = CAP + slot; i < deg; i += ES) {
        int s = csr[begin + i];
        float e = el[s * H + h] + er_nh;
        e = e > 0.f ? e : NEG_SLOPE * e;
        float wex = __expf(e - m);
        unsigned int f = frow[(size_t)s * (HD / 2) + colOff];
        accx += wex * __uint_as_float(f << 16);
        accy += wex * __uint_as_float(f & 0xffff0000u);
    }
#pragma unroll
    for (int o = L; o < 64; o <<= 1) {
        accx += __shfl_xor(accx, o);
        accy += __shfl_xor(accy, o);
    }
    if (lane < L) {
        float2 o2 = make_float2(accx * inv + bias[h * D + 2 * p],
                                accy * inv + bias[h * D + 2 * p + 1]);
        *(float2*)&out[(size_t)n * HD + h * D + 2 * p] = o2;
    }
}

// ---------------- launch ----------------

extern "C" void kernel_launch(void* const* d_in, const int* in_sizes, int n_in,
                              void* d_out, int out_size, void* d_ws, size_t ws_size,
                              hipStream_t stream) {
    const float* inputs = (const float*)d_in[0];
    const float* W0 = (const float*)d_in[1];
    const float* al0 = (const float*)d_in[2];
    const float* ar0 = (const float*)d_in[3];
    const float* b0 = (const float*)d_in[4];
    const float* W1 = (const float*)d_in[5];
    const float* al1 = (const float*)d_in[6];
    const float* ar1 = (const float*)d_in[7];
    const float* b1 = (const float*)d_in[8];
    const float* W2 = (const float*)d_in[9];
    const float* al2 = (const float*)d_in[10];
    const float* ar2 = (const float*)d_in[11];
    const float* b2 = (const float*)d_in[12];
    const int* src = (const int*)d_in[13];
    const int* dst = (const int*)d_in[14];

    const int IN_DIM = 128;
    const int N = in_sizes[0] / IN_DIM;  // 50000
    const int E = in_sizes[13];          // 800000
    float* out = (float*)d_out;

    char* base = (char*)d_ws;
    size_t o = 0;
    auto carve = [&](size_t bytes) -> void* {
        void* p = base + o;
        o += (bytes + 255) & ~(size_t)255;
        return p;
    };
    int* off = (int*)carve((size_t)(N + 1) * sizeof(int));
    int* cursor = (int*)carve((size_t)N * sizeof(int));
    int* chunkSum = (int*)carve(64 * sizeof(int));
    int* chunkOff = (int*)carve(64 * sizeof(int));
    int* csr = (int*)carve((size_t)E * sizeof(int));
    float* el = (float*)carve((size_t)N * 4 * sizeof(float));
    float* er = (float*)carve((size_t)N * 4 * sizeof(float));
    unsigned short* featb = (unsigned short*)carve((size_t)N * 256 * sizeof(unsigned short));
    unsigned short* a0hi = (unsigned short*)carve((size_t)N * 128 * sizeof(unsigned short));
    unsigned short* a0lo = (unsigned short*)carve((size_t)N * 128 * sizeof(unsigned short));
    unsigned short* hbhi = (unsigned short*)carve((size_t)N * 256 * sizeof(unsigned short));
    unsigned short* hblo = (unsigned short*)carve((size_t)N * 256 * sizeof(unsigned short));
    unsigned short* wt0hi = (unsigned short*)carve((size_t)128 * 256 * sizeof(unsigned short));
    unsigned short* wt0lo = (unsigned short*)carve((size_t)128 * 256 * sizeof(unsigned short));
    unsigned short* wt1hi = (unsigned short*)carve((size_t)256 * 256 * sizeof(unsigned short));
    unsigned short* wt1lo = (unsigned short*)carve((size_t)256 * 256 * sizeof(unsigned short));

    // ---- CSR build ----
    hipMemsetAsync(off, 0, (size_t)(N + 1) * sizeof(int), stream);
    int egrid = (E + 255) / 256;
    count_deg<<<egrid, 256, 0, stream>>>(dst, off, E);
    int nchunks = (N + 2047) / 2048;
    scan_chunk<<<nchunks, 256, 0, stream>>>(off, chunkSum, N);
    scan_tail<<<1, 64, 0, stream>>>(chunkSum, chunkOff, nchunks, off, N, E);
    add_chunk_off<<<(N + 255) / 256, 256, 0, stream>>>(off, cursor, chunkOff, N);
    scatter_edges<<<egrid, 256, 0, stream>>>(src, dst, cursor, csr, E);

    // ---- W + A prep ----
    wsplit<<<(128 * 256 + 255) / 256, 256, 0, stream>>>(W0, wt0hi, wt0lo, 128, 256);
    wsplit<<<(256 * 256 + 255) / 256, 256, 0, stream>>>(W1, wt1hi, wt1lo, 256, 256);
    asplit<<<(N * 32 + 255) / 256, 256, 0, stream>>>(inputs, a0hi, a0lo, N * 32);

    // ---- Layer 0: 128 -> 4x64 (MFMA, fused elr) ----
    {
        dim3 grid(256 / 128, (N + 127) / 128);
        gemm_mfma<<<grid, 256, 0, stream>>>(a0hi, a0lo, wt0hi, wt0lo, featb, el, er, al0, ar0, N, 128, 256);
        agg4_kernel<64, 24, 4><<<(N + 3) / 4, 256, 0, stream>>>(featb, el, er, b0, off, csr, hbhi, hblo, N);
    }
    // ---- Layer 1: 256 -> 4x64 (MFMA, fused elr) ----
    {
        dim3 grid(256 / 128, (N + 127) / 128);
        gemm_mfma<<<grid, 256, 0, stream>>>(hbhi, hblo, wt1hi, wt1lo, featb, el, er, al1, ar1, N, 256, 256);
        agg4_kernel<64, 24, 4><<<(N + 3) / 4, 256, 0, stream>>>(featb, el, er, b1, off, csr, hbhi, hblo, N);
    }
    // ---- Layer 2: 256 -> 1x16 (fp32 GEMM fused with elr) ----
    {
        dim3 grid(1, (N + 63) / 64);
        gemm_kernel<<<grid, 256, 0, stream>>>(hbhi, hblo, W2, al2, ar2, el, er, featb, N, 256, 16);
        agg_kernel<1, 16, 512, 2><<<N, 64, 0, stream>>>(featb, el, er, b2, off, csr, out, N);
    }
}

// Round 9
// 484.530 us; speedup vs baseline: 1.1125x; 1.1125x over previous
//
#include <hip/hip_runtime.h>
#include <hip/hip_bf16.h>
#include <math.h>

// ---------------------------------------------------------------------------
// GAT 3-layer forward.
// R9: revert agg4 to the R7 structure (R8's register-prefetch regressed:
// compiler spilled/serialized the PF=24 conditional loads). Keep R8's
// layer-2 gemm+elr fusion and the pre-split hi/lo pipeline. New: agg16
// repacked as 4 nodes per 256-thread block (was 1 wave per 64-thread block).
// agg4 is ~85% of the per-CU vmem ceiling (410 MB logical gather @ ~10 B/cyc/CU).
// ---------------------------------------------------------------------------

#define NEG_SLOPE 0.2f

typedef __attribute__((ext_vector_type(8))) short v8s;   // 8 bf16 in 4 VGPRs
typedef __attribute__((ext_vector_type(4))) float f32x4;

// ---------------- CSR build ----------------

__global__ __launch_bounds__(256) void count_deg(const int* __restrict__ dst,
                                                 int* __restrict__ deg, int E) {
    int e = blockIdx.x * 256 + threadIdx.x;
    if (e < E) atomicAdd(&deg[dst[e]], 1);
}

__global__ __launch_bounds__(256) void scan_chunk(int* __restrict__ off,
                                                  int* __restrict__ chunkSum, int N) {
    __shared__ int sdata[256];
    int tid = threadIdx.x;
    int base = blockIdx.x * 2048 + tid * 8;
    int v[8];
    int tsum = 0;
#pragma unroll
    for (int j = 0; j < 8; ++j) {
        int idx = base + j;
        v[j] = (idx < N) ? off[idx] : 0;
        tsum += v[j];
    }
    sdata[tid] = tsum;
    __syncthreads();
    for (int o = 1; o < 256; o <<= 1) {
        int t = (tid >= o) ? sdata[tid - o] : 0;
        __syncthreads();
        sdata[tid] += t;
        __syncthreads();
    }
    int run = sdata[tid] - tsum;
#pragma unroll
    for (int j = 0; j < 8; ++j) {
        int idx = base + j;
        if (idx < N) off[idx] = run;
        run += v[j];
    }
    if (tid == 255) chunkSum[blockIdx.x] = sdata[255];
}

__global__ void scan_tail(const int* __restrict__ chunkSum, int* __restrict__ chunkOff,
                          int nchunks, int* __restrict__ off, int N, int E) {
    if (threadIdx.x == 0 && blockIdx.x == 0) {
        int run = 0;
        for (int c = 0; c < nchunks; ++c) { chunkOff[c] = run; run += chunkSum[c]; }
        off[N] = E;
    }
}

__global__ __launch_bounds__(256) void add_chunk_off(int* __restrict__ off,
                                                     int* __restrict__ cursor,
                                                     const int* __restrict__ chunkOff, int N) {
    int i = blockIdx.x * 256 + threadIdx.x;
    if (i < N) {
        int v = off[i] + chunkOff[i >> 11];
        off[i] = v;
        cursor[i] = v;
    }
}

__global__ __launch_bounds__(256) void scatter_edges(const int* __restrict__ src,
                                                     const int* __restrict__ dst,
                                                     int* __restrict__ cursor,
                                                     int* __restrict__ csr, int E) {
    int e = blockIdx.x * 256 + threadIdx.x;
    if (e < E) {
        int d = dst[e];
        int pos = atomicAdd(&cursor[d], 1);
        csr[pos] = src[e];
    }
}

// ---------------- bf16 split helpers ----------------

__device__ __forceinline__ unsigned short bf16_rne(float x) {
    unsigned int u = __float_as_uint(x);
    return (unsigned short)((u + 0x7fffu + ((u >> 16) & 1u)) >> 16);
}

__device__ __forceinline__ void split2(float v, unsigned short& h, unsigned short& l) {
    unsigned int u = __float_as_uint(v);
    unsigned int uh = (u + 0x7fffu + ((u >> 16) & 1u)) & 0xffff0000u;
    h = (unsigned short)(uh >> 16);
    l = bf16_rne(v - __uint_as_float(uh));
}

__global__ __launch_bounds__(256) void wsplit(const float* __restrict__ W,
                                              unsigned short* __restrict__ thi,
                                              unsigned short* __restrict__ tlo,
                                              int F, int K) {
    int idx = blockIdx.x * 256 + threadIdx.x;
    if (idx >= F * K) return;
    int f = idx / K, k = idx % K;
    float v = W[idx];
    unsigned short h, l;
    split2(v, h, l);
    thi[k * F + f] = h;
    tlo[k * F + f] = l;
}

__global__ __launch_bounds__(256) void asplit(const float* __restrict__ A,
                                              unsigned short* __restrict__ hi,
                                              unsigned short* __restrict__ lo,
                                              int total4) {
    int i = blockIdx.x * 256 + threadIdx.x;
    if (i >= total4) return;
    float4 v = *(const float4*)&A[(size_t)i * 4];
    unsigned short h[4], l[4];
    split2(v.x, h[0], l[0]); split2(v.y, h[1], l[1]);
    split2(v.z, h[2], l[2]); split2(v.w, h[3], l[3]);
    *(ushort4*)&hi[(size_t)i * 4] = make_ushort4(h[0], h[1], h[2], h[3]);
    *(ushort4*)&lo[(size_t)i * 4] = make_ushort4(l[0], l[1], l[2], l[3]);
}

// ---------------- MFMA GEMM (pre-split A) fused with el/er ----------------

__global__ __launch_bounds__(256) void gemm_mfma(const unsigned short* __restrict__ Ahi,
                                                 const unsigned short* __restrict__ Alo,
                                                 const unsigned short* __restrict__ Bthi,
                                                 const unsigned short* __restrict__ Btlo,
                                                 unsigned short* __restrict__ featb,
                                                 float* __restrict__ el,
                                                 float* __restrict__ er,
                                                 const float* __restrict__ al,
                                                 const float* __restrict__ ar,
                                                 int N, int F, int K) {
    __shared__ unsigned short As[2][128][40];
    __shared__ unsigned short Bs[2][128][40];
    int tid = threadIdx.x;
    int lane = tid & 63, w = tid >> 6;
    int wr = (w >> 1) * 64, wc = (w & 1) * 64;
    int lr = lane & 15, lq = lane >> 4;
    int m0 = blockIdx.y * 128, n0 = blockIdx.x * 128;
    f32x4 acc[4][4] = {};

    for (int k0 = 0; k0 < F; k0 += 32) {
        __syncthreads();
#pragma unroll
        for (int i = 0; i < 4; ++i) {
            int c = i * 256 + tid;
            int s = c >> 9, r = (c >> 2) & 127, cc = c & 3;
            const unsigned short* Asrc = s ? Alo : Ahi;
            uint4 v = make_uint4(0u, 0u, 0u, 0u);
            int gr = m0 + r;
            if (gr < N) v = *(const uint4*)&Asrc[(size_t)gr * F + k0 + cc * 8];
            *(uint4*)&As[s][r][cc * 8] = v;
        }
#pragma unroll
        for (int i = 0; i < 4; ++i) {
            int c = i * 256 + tid;
            int s = c >> 9, r = (c >> 2) & 127, cc = c & 3;
            const unsigned short* B = s ? Btlo : Bthi;
            uint4 bv = *(const uint4*)&B[(size_t)(n0 + r) * F + k0 + cc * 8];
            *(uint4*)&Bs[s][r][cc * 8] = bv;
        }
        __syncthreads();

        v8s af[2][4], bf[2][4];
#pragma unroll
        for (int mt = 0; mt < 4; ++mt) {
            af[0][mt] = *(const v8s*)&As[0][wr + mt * 16 + lr][lq * 8];
            af[1][mt] = *(const v8s*)&As[1][wr + mt * 16 + lr][lq * 8];
        }
#pragma unroll
        for (int nt = 0; nt < 4; ++nt) {
            bf[0][nt] = *(const v8s*)&Bs[0][wc + nt * 16 + lr][lq * 8];
            bf[1][nt] = *(const v8s*)&Bs[1][wc + nt * 16 + lr][lq * 8];
        }
#pragma unroll
        for (int mt = 0; mt < 4; ++mt)
#pragma unroll
            for (int nt = 0; nt < 4; ++nt) {
                acc[mt][nt] = __builtin_amdgcn_mfma_f32_16x16x32_bf16(af[0][mt], bf[0][nt], acc[mt][nt], 0, 0, 0);
                acc[mt][nt] = __builtin_amdgcn_mfma_f32_16x16x32_bf16(af[0][mt], bf[1][nt], acc[mt][nt], 0, 0, 0);
                acc[mt][nt] = __builtin_amdgcn_mfma_f32_16x16x32_bf16(af[1][mt], bf[0][nt], acc[mt][nt], 0, 0, 0);
            }
    }

    int h = (n0 + wc) >> 6;
    float alw[4], arw[4];
#pragma unroll
    for (int nt = 0; nt < 4; ++nt) {
        int d = nt * 16 + lr;
        alw[nt] = al[h * 64 + d];
        arw[nt] = ar[h * 64 + d];
    }
#pragma unroll
    for (int mt = 0; mt < 4; ++mt) {
#pragma unroll
        for (int r = 0; r < 4; ++r) {
            float se = 0.f, sr = 0.f;
#pragma unroll
            for (int nt = 0; nt < 4; ++nt) {
                float v = acc[mt][nt][r];
                se += v * alw[nt];
                sr += v * arw[nt];
            }
#pragma unroll
            for (int o = 8; o >= 1; o >>= 1) {
                se += __shfl_xor(se, o);
                sr += __shfl_xor(sr, o);
            }
            int row = m0 + wr + mt * 16 + lq * 4 + r;
            if (lr == 0 && row < N) {
                el[(size_t)row * 4 + h] = se;
                er[(size_t)row * 4 + h] = sr;
            }
        }
    }
#pragma unroll
    for (int mt = 0; mt < 4; ++mt) {
#pragma unroll
        for (int nt = 0; nt < 4; ++nt) {
            int col = n0 + wc + nt * 16 + lr;
#pragma unroll
            for (int r = 0; r < 4; ++r) {
                int row = m0 + wr + mt * 16 + lq * 4 + r;
                if (row < N) featb[(size_t)row * K + col] = bf16_rne(acc[mt][nt][r]);
            }
        }
    }
}

// ---------------- fp32 GEMM (layer 2, K=16) fused with el/er + bf16 ------

__global__ __launch_bounds__(256) void gemm_kernel(const unsigned short* __restrict__ Ahi,
                                                   const unsigned short* __restrict__ Alo,
                                                   const float* __restrict__ W,
                                                   const float* __restrict__ al2,
                                                   const float* __restrict__ ar2,
                                                   float* __restrict__ el,
                                                   float* __restrict__ er,
                                                   unsigned short* __restrict__ featb,
                                                   int N, int F, int K) {
    __shared__ __align__(16) float As2[16][68];
    __shared__ __align__(16) float Ws2[16][64];
    int tid = threadIdx.x;
    int tx = tid & 15, ty = tid >> 4;
    int r0 = blockIdx.y * 64;
    int arow = tid >> 2, akq = tid & 3;
    int wk = tid >> 4, wcq = tid & 15;
    float acc[4][4] = {};

    for (int k0 = 0; k0 < F; k0 += 16) {
        float4 av = make_float4(0.f, 0.f, 0.f, 0.f);
        int gr = r0 + arow;
        if (gr < N) {
            size_t base = (size_t)gr * F + k0 + akq * 4;
            uint2 vh = *(const uint2*)&Ahi[base];
            uint2 vl = *(const uint2*)&Alo[base];
            av.x = __uint_as_float(vh.x << 16) + __uint_as_float(vl.x << 16);
            av.y = __uint_as_float(vh.x & 0xffff0000u) + __uint_as_float(vl.x & 0xffff0000u);
            av.z = __uint_as_float(vh.y << 16) + __uint_as_float(vl.y << 16);
            av.w = __uint_as_float(vh.y & 0xffff0000u) + __uint_as_float(vl.y & 0xffff0000u);
        }
        float4 wv = make_float4(0.f, 0.f, 0.f, 0.f);
        int gc = wcq * 4;
        if (gc < K) wv = *(const float4*)&W[(size_t)(k0 + wk) * K + gc];
        __syncthreads();
        As2[akq * 4 + 0][arow] = av.x;
        As2[akq * 4 + 1][arow] = av.y;
        As2[akq * 4 + 2][arow] = av.z;
        As2[akq * 4 + 3][arow] = av.w;
        *(float4*)&Ws2[wk][wcq * 4] = wv;
        __syncthreads();
#pragma unroll
        for (int k = 0; k < 16; ++k) {
            float4 a = *(const float4*)&As2[k][ty * 4];
            float4 wv2 = *(const float4*)&Ws2[k][tx * 4];
            acc[0][0] += a.x * wv2.x; acc[0][1] += a.x * wv2.y; acc[0][2] += a.x * wv2.z; acc[0][3] += a.x * wv2.w;
            acc[1][0] += a.y * wv2.x; acc[1][1] += a.y * wv2.y; acc[1][2] += a.y * wv2.z; acc[1][3] += a.y * wv2.w;
            acc[2][0] += a.z * wv2.x; acc[2][1] += a.z * wv2.y; acc[2][2] += a.z * wv2.z; acc[2][3] += a.z * wv2.w;
            acc[3][0] += a.w * wv2.x; acc[3][1] += a.w * wv2.y; acc[3][2] += a.w * wv2.z; acc[3][3] += a.w * wv2.w;
        }
    }
    float alv[4] = {0.f, 0.f, 0.f, 0.f}, arv[4] = {0.f, 0.f, 0.f, 0.f};
    if (tx < 4) {
#pragma unroll
        for (int c = 0; c < 4; ++c) {
            alv[c] = al2[tx * 4 + c];
            arv[c] = ar2[tx * 4 + c];
        }
    }
#pragma unroll
    for (int i = 0; i < 4; ++i) {
        int gr = r0 + ty * 4 + i;
        float pe = 0.f, pr = 0.f;
        if (tx < 4) {
#pragma unroll
            for (int c = 0; c < 4; ++c) {
                pe += acc[i][c] * alv[c];
                pr += acc[i][c] * arv[c];
            }
        }
        pe += __shfl_xor(pe, 1); pr += __shfl_xor(pr, 1);
        pe += __shfl_xor(pe, 2); pr += __shfl_xor(pr, 2);
        if (tx == 0 && gr < N) {
            el[gr] = pe;
            er[gr] = pr;
        }
        if (tx < 4 && gr < N) {
            ushort4 o4 = make_ushort4(bf16_rne(acc[i][0]), bf16_rne(acc[i][1]),
                                      bf16_rne(acc[i][2]), bf16_rne(acc[i][3]));
            *(ushort4*)&featb[(size_t)gr * 16 + tx * 4] = o4;
        }
    }
}

// ---------------- agg for H=4, D=64: wave-per-node (R7 structure) ---------

template <int CAP, int U>
__global__ __launch_bounds__(256) void agg4_kernel(const unsigned short* __restrict__ featb,
                                                   const float* __restrict__ el,
                                                   const float* __restrict__ er,
                                                   const float* __restrict__ bias,
                                                   const int* __restrict__ off,
                                                   const int* __restrict__ csr,
                                                   unsigned short* __restrict__ outhi,
                                                   unsigned short* __restrict__ outlo, int N) {
    __shared__ float s_alpha[4][4][CAP];  // [wave][head][edge]
    __shared__ int s_src[4][CAP];
    int w = threadIdx.x >> 6;
    int lane = threadIdx.x & 63;
    int n = blockIdx.x * 4 + w;
    if (n >= N) return;
    int begin = off[n];
    int deg = off[n + 1] - begin;
    float4 ern = *(const float4*)&er[(size_t)n * 4];

    float m0 = -INFINITY, m1 = -INFINITY, m2 = -INFINITY, m3 = -INFINITY;
    float s0 = 0.f, s1 = 0.f, s2 = 0.f, s3 = 0.f;

    if (deg <= 64) {
        bool act = lane < deg;
        int s = 0;
        float e0 = -INFINITY, e1 = -INFINITY, e2 = -INFINITY, e3 = -INFINITY;
        if (act) {
            s = csr[begin + lane];
            float4 e = *(const float4*)&el[(size_t)s * 4];
            e0 = e.x + ern.x; e1 = e.y + ern.y; e2 = e.z + ern.z; e3 = e.w + ern.w;
            e0 = e0 > 0.f ? e0 : NEG_SLOPE * e0;
            e1 = e1 > 0.f ? e1 : NEG_SLOPE * e1;
            e2 = e2 > 0.f ? e2 : NEG_SLOPE * e2;
            e3 = e3 > 0.f ? e3 : NEG_SLOPE * e3;
        }
        m0 = e0; m1 = e1; m2 = e2; m3 = e3;
#pragma unroll
        for (int o = 32; o >= 1; o >>= 1) {
            m0 = fmaxf(m0, __shfl_xor(m0, o));
            m1 = fmaxf(m1, __shfl_xor(m1, o));
            m2 = fmaxf(m2, __shfl_xor(m2, o));
            m3 = fmaxf(m3, __shfl_xor(m3, o));
        }
        if (act) {
            s0 = __expf(e0 - m0); s1 = __expf(e1 - m1);
            s2 = __expf(e2 - m2); s3 = __expf(e3 - m3);
            s_src[w][lane] = s;
            s_alpha[w][0][lane] = s0;
            s_alpha[w][1][lane] = s1;
            s_alpha[w][2][lane] = s2;
            s_alpha[w][3][lane] = s3;
        }
#pragma unroll
        for (int o = 32; o >= 1; o >>= 1) {
            s0 += __shfl_xor(s0, o); s1 += __shfl_xor(s1, o);
            s2 += __shfl_xor(s2, o); s3 += __shfl_xor(s3, o);
        }
    } else {
        for (int i = lane; i < deg; i += 64) {
            int s = csr[begin + i];
            float4 e = *(const float4*)&el[(size_t)s * 4];
            float e0 = e.x + ern.x, e1 = e.y + ern.y, e2 = e.z + ern.z, e3 = e.w + ern.w;
            e0 = e0 > 0.f ? e0 : NEG_SLOPE * e0;
            e1 = e1 > 0.f ? e1 : NEG_SLOPE * e1;
            e2 = e2 > 0.f ? e2 : NEG_SLOPE * e2;
            e3 = e3 > 0.f ? e3 : NEG_SLOPE * e3;
            if (i < CAP) {
                s_src[w][i] = s;
                s_alpha[w][0][i] = e0; s_alpha[w][1][i] = e1;
                s_alpha[w][2][i] = e2; s_alpha[w][3][i] = e3;
            }
            m0 = fmaxf(m0, e0); m1 = fmaxf(m1, e1);
            m2 = fmaxf(m2, e2); m3 = fmaxf(m3, e3);
        }
#pragma unroll
        for (int o = 32; o >= 1; o >>= 1) {
            m0 = fmaxf(m0, __shfl_xor(m0, o));
            m1 = fmaxf(m1, __shfl_xor(m1, o));
            m2 = fmaxf(m2, __shfl_xor(m2, o));
            m3 = fmaxf(m3, __shfl_xor(m3, o));
        }
        for (int i = lane; i < deg; i += 64) {
            float e0, e1, e2, e3;
            if (i < CAP) {
                e0 = s_alpha[w][0][i]; e1 = s_alpha[w][1][i];
                e2 = s_alpha[w][2][i]; e3 = s_alpha[w][3][i];
            } else {
                int s = csr[begin + i];
                float4 e = *(const float4*)&el[(size_t)s * 4];
                e0 = e.x + ern.x; e1 = e.y + ern.y; e2 = e.z + ern.z; e3 = e.w + ern.w;
                e0 = e0 > 0.f ? e0 : NEG_SLOPE * e0;
                e1 = e1 > 0.f ? e1 : NEG_SLOPE * e1;
                e2 = e2 > 0.f ? e2 : NEG_SLOPE * e2;
                e3 = e3 > 0.f ? e3 : NEG_SLOPE * e3;
            }
            e0 = __expf(e0 - m0); e1 = __expf(e1 - m1);
            e2 = __expf(e2 - m2); e3 = __expf(e3 - m3);
            if (i < CAP) {
                s_alpha[w][0][i] = e0; s_alpha[w][1][i] = e1;
                s_alpha[w][2][i] = e2; s_alpha[w][3][i] = e3;
            }
            s0 += e0; s1 += e1; s2 += e2; s3 += e3;
        }
#pragma unroll
        for (int o = 32; o >= 1; o >>= 1) {
            s0 += __shfl_xor(s0, o); s1 += __shfl_xor(s1, o);
            s2 += __shfl_xor(s2, o); s3 += __shfl_xor(s3, o);
        }
    }

    float inv0 = deg > 0 ? 1.f / s0 : 0.f;
    float inv1 = deg > 0 ? 1.f / s1 : 0.f;
    float inv2 = deg > 0 ? 1.f / s2 : 0.f;
    float inv3 = deg > 0 ? 1.f / s3 : 0.f;

    int hsel = lane >> 5;
    int dcap = deg < CAP ? deg : CAP;
    const unsigned int* frow = (const unsigned int*)featb;
    float a0 = 0.f, a1 = 0.f, a2 = 0.f, a3 = 0.f;
    int j = 0;
    for (; j + U <= dcap; j += U) {
        int s[U];
        unsigned int f0[U], f1[U];
        float aA[U], aB[U];
#pragma unroll
        for (int u = 0; u < U; ++u) s[u] = s_src[w][j + u];
#pragma unroll
        for (int u = 0; u < U; ++u) {
            const unsigned int* rp = frow + (size_t)s[u] * 128;
            f0[u] = rp[lane];
            f1[u] = rp[64 + lane];
        }
#pragma unroll
        for (int u = 0; u < U; ++u) {
            aA[u] = s_alpha[w][hsel][j + u];
            aB[u] = s_alpha[w][2 + hsel][j + u];
        }
#pragma unroll
        for (int u = 0; u < U; ++u) {
            a0 += aA[u] * __uint_as_float(f0[u] << 16);
            a1 += aA[u] * __uint_as_float(f0[u] & 0xffff0000u);
            a2 += aB[u] * __uint_as_float(f1[u] << 16);
            a3 += aB[u] * __uint_as_float(f1[u] & 0xffff0000u);
        }
    }
    for (; j < dcap; ++j) {
        int s = s_src[w][j];
        const unsigned int* rp = frow + (size_t)s * 128;
        unsigned int f0v = rp[lane], f1v = rp[64 + lane];
        float aA = s_alpha[w][hsel][j], aB = s_alpha[w][2 + hsel][j];
        a0 += aA * __uint_as_float(f0v << 16);
        a1 += aA * __uint_as_float(f0v & 0xffff0000u);
        a2 += aB * __uint_as_float(f1v << 16);
        a3 += aB * __uint_as_float(f1v & 0xffff0000u);
    }
    for (int i = CAP; i < deg; ++i) {
        int s = csr[begin + i];
        float4 e = *(const float4*)&el[(size_t)s * 4];
        float e0 = e.x + ern.x, e1 = e.y + ern.y, e2 = e.z + ern.z, e3 = e.w + ern.w;
        e0 = e0 > 0.f ? e0 : NEG_SLOPE * e0;
        e1 = e1 > 0.f ? e1 : NEG_SLOPE * e1;
        e2 = e2 > 0.f ? e2 : NEG_SLOPE * e2;
        e3 = e3 > 0.f ? e3 : NEG_SLOPE * e3;
        float x0 = __expf(e0 - m0), x1 = __expf(e1 - m1);
        float x2 = __expf(e2 - m2), x3 = __expf(e3 - m3);
        float aA = hsel ? x1 : x0, aB = hsel ? x3 : x2;
        const unsigned int* rp = frow + (size_t)s * 128;
        unsigned int f0v = rp[lane], f1v = rp[64 + lane];
        a0 += aA * __uint_as_float(f0v << 16);
        a1 += aA * __uint_as_float(f0v & 0xffff0000u);
        a2 += aB * __uint_as_float(f1v << 16);
        a3 += aB * __uint_as_float(f1v & 0xffff0000u);
    }
    float invA = hsel ? inv1 : inv0;
    float invB = hsel ? inv3 : inv2;
    float o00 = a0 * invA + bias[2 * lane];
    float o01 = a1 * invA + bias[2 * lane + 1];
    float o10 = a2 * invB + bias[128 + 2 * lane];
    float o11 = a3 * invB + bias[128 + 2 * lane + 1];
    unsigned short h00, l00, h01, l01, h10, l10, h11, l11;
    split2(o00, h00, l00); split2(o01, h01, l01);
    split2(o10, h10, l10); split2(o11, h11, l11);
    unsigned int* ophi = (unsigned int*)outhi;
    unsigned int* oplo = (unsigned int*)outlo;
    ophi[(size_t)n * 128 + lane] = (unsigned int)h00 | ((unsigned int)h01 << 16);
    oplo[(size_t)n * 128 + lane] = (unsigned int)l00 | ((unsigned int)l01 << 16);
    ophi[(size_t)n * 128 + 64 + lane] = (unsigned int)h10 | ((unsigned int)h11 << 16);
    oplo[(size_t)n * 128 + 64 + lane] = (unsigned int)l10 | ((unsigned int)l11 << 16);
}

// ---------------- agg for H=1, D=16 (layer 2): 4 nodes/block --------------
// Wave-per-node, 8 edge slots/wave (slot covers cols 2p,2p+1 via bf16x2).

template <int CAP>
__global__ __launch_bounds__(256) void agg16_kernel(const unsigned short* __restrict__ featb,
                                                    const float* __restrict__ el,
                                                    const float* __restrict__ er,
                                                    const float* __restrict__ bias,
                                                    const int* __restrict__ off,
                                                    const int* __restrict__ csr,
                                                    float* __restrict__ out, int N) {
    __shared__ float s_alpha[4][CAP];
    __shared__ int s_src[4][CAP];
    int w = threadIdx.x >> 6;
    int lane = threadIdx.x & 63;
    int n = blockIdx.x * 4 + w;
    if (n >= N) return;
    int begin = off[n];
    int deg = off[n + 1] - begin;
    float ern = er[n];

    float m = -INFINITY, ssum = 0.f;
    if (deg <= 64) {
        bool act = lane < deg;
        int s = 0;
        float e = -INFINITY;
        if (act) {
            s = csr[begin + lane];
            e = el[s] + ern;
            e = e > 0.f ? e : NEG_SLOPE * e;
        }
        m = e;
#pragma unroll
        for (int o = 32; o >= 1; o >>= 1) m = fmaxf(m, __shfl_xor(m, o));
        float x = 0.f;
        if (act) {
            x = __expf(e - m);
            s_src[w][lane] = s;
            s_alpha[w][lane] = x;
        }
        ssum = x;
#pragma unroll
        for (int o = 32; o >= 1; o >>= 1) ssum += __shfl_xor(ssum, o);
    } else {
        for (int i = lane; i < deg; i += 64) {
            int s = csr[begin + i];
            float e = el[s] + ern;
            e = e > 0.f ? e : NEG_SLOPE * e;
            if (i < CAP) { s_src[w][i] = s; s_alpha[w][i] = e; }
            m = fmaxf(m, e);
        }
#pragma unroll
        for (int o = 32; o >= 1; o >>= 1) m = fmaxf(m, __shfl_xor(m, o));
        for (int i = lane; i < deg; i += 64) {
            float e;
            if (i < CAP) e = s_alpha[w][i];
            else {
                int s = csr[begin + i];
                e = el[s] + ern;
                e = e > 0.f ? e : NEG_SLOPE * e;
            }
            float x = __expf(e - m);
            if (i < CAP) s_alpha[w][i] = x;
            ssum += x;
        }
#pragma unroll
        for (int o = 32; o >= 1; o >>= 1) ssum += __shfl_xor(ssum, o);
    }
    float inv = deg > 0 ? 1.f / ssum : 0.f;

    // phase 3: 8 slots x 8 lanes; featb row = 16 bf16 = 8 dwords
    int slot = lane >> 3, p = lane & 7;
    int dcap = deg < CAP ? deg : CAP;
    const unsigned int* frow = (const unsigned int*)featb;
    float ax = 0.f, ay = 0.f;
    for (int j = slot; j < dcap; j += 8) {
        int s = s_src[w][j];
        float a = s_alpha[w][j];
        unsigned int f = frow[(size_t)s * 8 + p];
        ax += a * __uint_as_float(f << 16);
        ay += a * __uint_as_float(f & 0xffff0000u);
    }
    for (int i = CAP + slot; i < deg; i += 8) {
        int s = csr[begin + i];
        float e = el[s] + ern;
        e = e > 0.f ? e : NEG_SLOPE * e;
        float x = __expf(e - m);
        unsigned int f = frow[(size_t)s * 8 + p];
        ax += x * __uint_as_float(f << 16);
        ay += x * __uint_as_float(f & 0xffff0000u);
    }
#pragma unroll
    for (int o = 8; o < 64; o <<= 1) {
        ax += __shfl_xor(ax, o);
        ay += __shfl_xor(ay, o);
    }
    if (lane < 8) {
        float2 o2 = make_float2(ax * inv + bias[2 * p], ay * inv + bias[2 * p + 1]);
        *(float2*)&out[(size_t)n * 16 + 2 * p] = o2;
    }
}

// ---------------- launch ----------------

extern "C" void kernel_launch(void* const* d_in, const int* in_sizes, int n_in,
                              void* d_out, int out_size, void* d_ws, size_t ws_size,
                              hipStream_t stream) {
    const float* inputs = (const float*)d_in[0];
    const float* W0 = (const float*)d_in[1];
    const float* al0 = (const float*)d_in[2];
    const float* ar0 = (const float*)d_in[3];
    const float* b0 = (const float*)d_in[4];
    const float* W1 = (const float*)d_in[5];
    const float* al1 = (const float*)d_in[6];
    const float* ar1 = (const float*)d_in[7];
    const float* b1 = (const float*)d_in[8];
    const float* W2 = (const float*)d_in[9];
    const float* al2 = (const float*)d_in[10];
    const float* ar2 = (const float*)d_in[11];
    const float* b2 = (const float*)d_in[12];
    const int* src = (const int*)d_in[13];
    const int* dst = (const int*)d_in[14];

    const int IN_DIM = 128;
    const int N = in_sizes[0] / IN_DIM;  // 50000
    const int E = in_sizes[13];          // 800000
    float* out = (float*)d_out;

    char* base = (char*)d_ws;
    size_t o = 0;
    auto carve = [&](size_t bytes) -> void* {
        void* p = base + o;
        o += (bytes + 255) & ~(size_t)255;
        return p;
    };
    int* off = (int*)carve((size_t)(N + 1) * sizeof(int));
    int* cursor = (int*)carve((size_t)N * sizeof(int));
    int* chunkSum = (int*)carve(64 * sizeof(int));
    int* chunkOff = (int*)carve(64 * sizeof(int));
    int* csr = (int*)carve((size_t)E * sizeof(int));
    float* el = (float*)carve((size_t)N * 4 * sizeof(float));
    float* er = (float*)carve((size_t)N * 4 * sizeof(float));
    unsigned short* featb = (unsigned short*)carve((size_t)N * 256 * sizeof(unsigned short));
    unsigned short* a0hi = (unsigned short*)carve((size_t)N * 128 * sizeof(unsigned short));
    unsigned short* a0lo = (unsigned short*)carve((size_t)N * 128 * sizeof(unsigned short));
    unsigned short* hbhi = (unsigned short*)carve((size_t)N * 256 * sizeof(unsigned short));
    unsigned short* hblo = (unsigned short*)carve((size_t)N * 256 * sizeof(unsigned short));
    unsigned short* wt0hi = (unsigned short*)carve((size_t)128 * 256 * sizeof(unsigned short));
    unsigned short* wt0lo = (unsigned short*)carve((size_t)128 * 256 * sizeof(unsigned short));
    unsigned short* wt1hi = (unsigned short*)carve((size_t)256 * 256 * sizeof(unsigned short));
    unsigned short* wt1lo = (unsigned short*)carve((size_t)256 * 256 * sizeof(unsigned short));

    // ---- CSR build ----
    hipMemsetAsync(off, 0, (size_t)(N + 1) * sizeof(int), stream);
    int egrid = (E + 255) / 256;
    count_deg<<<egrid, 256, 0, stream>>>(dst, off, E);
    int nchunks = (N + 2047) / 2048;
    scan_chunk<<<nchunks, 256, 0, stream>>>(off, chunkSum, N);
    scan_tail<<<1, 64, 0, stream>>>(chunkSum, chunkOff, nchunks, off, N, E);
    add_chunk_off<<<(N + 255) / 256, 256, 0, stream>>>(off, cursor, chunkOff, N);
    scatter_edges<<<egrid, 256, 0, stream>>>(src, dst, cursor, csr, E);

    // ---- W + A prep ----
    wsplit<<<(128 * 256 + 255) / 256, 256, 0, stream>>>(W0, wt0hi, wt0lo, 128, 256);
    wsplit<<<(256 * 256 + 255) / 256, 256, 0, stream>>>(W1, wt1hi, wt1lo, 256, 256);
    asplit<<<(N * 32 + 255) / 256, 256, 0, stream>>>(inputs, a0hi, a0lo, N * 32);

    // ---- Layer 0: 128 -> 4x64 (MFMA, fused elr) ----
    {
        dim3 grid(256 / 128, (N + 127) / 128);
        gemm_mfma<<<grid, 256, 0, stream>>>(a0hi, a0lo, wt0hi, wt0lo, featb, el, er, al0, ar0, N, 128, 256);
        agg4_kernel<64, 8><<<(N + 3) / 4, 256, 0, stream>>>(featb, el, er, b0, off, csr, hbhi, hblo, N);
    }
    // ---- Layer 1: 256 -> 4x64 (MFMA, fused elr) ----
    {
        dim3 grid(256 / 128, (N + 127) / 128);
        gemm_mfma<<<grid, 256, 0, stream>>>(hbhi, hblo, wt1hi, wt1lo, featb, el, er, al1, ar1, N, 256, 256);
        agg4_kernel<64, 8><<<(N + 3) / 4, 256, 0, stream>>>(featb, el, er, b1, off, csr, hbhi, hblo, N);
    }
    // ---- Layer 2: 256 -> 1x16 (fp32 GEMM fused with elr) ----
    {
        dim3 grid(1, (N + 63) / 64);
        gemm_kernel<<<grid, 256, 0, stream>>>(hbhi, hblo, W2, al2, ar2, el, er, featb, N, 256, 16);
        agg16_kernel<64><<<(N + 3) / 4, 256, 0, stream>>>(featb, el, er, b2, off, csr, out, N);
    }
}

// Round 10
// 445.924 us; speedup vs baseline: 1.2088x; 1.0866x over previous
//
#include <hip/hip_runtime.h>
#include <hip/hip_bf16.h>
#include <math.h>

// ---------------------------------------------------------------------------
// GAT 3-layer forward.
// R10: GEMM switched from 3-term split-bf16 to SINGLE-term f16 MFMA.
// Rationale: absmax has been pinned at 2^-10 since R1 even with bf16 (2^-9)
// rounding of all gathered feats; f16 operands (2^-11) are finer than that.
// MFMA work /3, staging /2, agg4 output writes /2 (one f16 array, no hi/lo).
// featb (gather operand) stays bf16.
// ---------------------------------------------------------------------------

#define NEG_SLOPE 0.2f

typedef __attribute__((ext_vector_type(8))) _Float16 v8h;  // 8 f16 in 4 VGPRs
typedef __attribute__((ext_vector_type(4))) float f32x4;

// ---------------- CSR build ----------------

__global__ __launch_bounds__(256) void count_deg(const int* __restrict__ dst,
                                                 int* __restrict__ deg, int E) {
    int e = blockIdx.x * 256 + threadIdx.x;
    if (e < E) atomicAdd(&deg[dst[e]], 1);
}

__global__ __launch_bounds__(256) void scan_chunk(int* __restrict__ off,
                                                  int* __restrict__ chunkSum, int N) {
    __shared__ int sdata[256];
    int tid = threadIdx.x;
    int base = blockIdx.x * 2048 + tid * 8;
    int v[8];
    int tsum = 0;
#pragma unroll
    for (int j = 0; j < 8; ++j) {
        int idx = base + j;
        v[j] = (idx < N) ? off[idx] : 0;
        tsum += v[j];
    }
    sdata[tid] = tsum;
    __syncthreads();
    for (int o = 1; o < 256; o <<= 1) {
        int t = (tid >= o) ? sdata[tid - o] : 0;
        __syncthreads();
        sdata[tid] += t;
        __syncthreads();
    }
    int run = sdata[tid] - tsum;
#pragma unroll
    for (int j = 0; j < 8; ++j) {
        int idx = base + j;
        if (idx < N) off[idx] = run;
        run += v[j];
    }
    if (tid == 255) chunkSum[blockIdx.x] = sdata[255];
}

__global__ void scan_tail(const int* __restrict__ chunkSum, int* __restrict__ chunkOff,
                          int nchunks, int* __restrict__ off, int N, int E) {
    if (threadIdx.x == 0 && blockIdx.x == 0) {
        int run = 0;
        for (int c = 0; c < nchunks; ++c) { chunkOff[c] = run; run += chunkSum[c]; }
        off[N] = E;
    }
}

__global__ __launch_bounds__(256) void add_chunk_off(int* __restrict__ off,
                                                     int* __restrict__ cursor,
                                                     const int* __restrict__ chunkOff, int N) {
    int i = blockIdx.x * 256 + threadIdx.x;
    if (i < N) {
        int v = off[i] + chunkOff[i >> 11];
        off[i] = v;
        cursor[i] = v;
    }
}

__global__ __launch_bounds__(256) void scatter_edges(const int* __restrict__ src,
                                                     const int* __restrict__ dst,
                                                     int* __restrict__ cursor,
                                                     int* __restrict__ csr, int E) {
    int e = blockIdx.x * 256 + threadIdx.x;
    if (e < E) {
        int d = dst[e];
        int pos = atomicAdd(&cursor[d], 1);
        csr[pos] = src[e];
    }
}

// ---------------- f16 helpers ----------------

__device__ __forceinline__ unsigned short bf16_rne(float x) {
    unsigned int u = __float_as_uint(x);
    return (unsigned short)((u + 0x7fffu + ((u >> 16) & 1u)) >> 16);
}

__device__ __forceinline__ unsigned short f16_bits(float x) {
    _Float16 h = (_Float16)x;
    union { _Float16 h; unsigned short u; } c;
    c.h = h;
    return c.u;
}

__device__ __forceinline__ float f16_to_f32(unsigned short u) {
    union { _Float16 h; unsigned short u; } c;
    c.u = u;
    return (float)c.h;
}

// W prep: W[F][K] fp32 -> Wt[K][F] f16 (transposed).
__global__ __launch_bounds__(256) void wcvt(const float* __restrict__ W,
                                            unsigned short* __restrict__ t,
                                            int F, int K) {
    int idx = blockIdx.x * 256 + threadIdx.x;
    if (idx >= F * K) return;
    int f = idx / K, k = idx % K;
    t[k * F + f] = f16_bits(W[idx]);
}

// A prep: fp32 stream -> f16, 4 elems/thread.
__global__ __launch_bounds__(256) void acvt(const float* __restrict__ A,
                                            unsigned short* __restrict__ h,
                                            int total4) {
    int i = blockIdx.x * 256 + threadIdx.x;
    if (i >= total4) return;
    float4 v = *(const float4*)&A[(size_t)i * 4];
    *(ushort4*)&h[(size_t)i * 4] = make_ushort4(f16_bits(v.x), f16_bits(v.y),
                                                f16_bits(v.z), f16_bits(v.w));
}

// ---------------- f16 MFMA GEMM fused with el/er + bf16 featb -------------
// C[N,K] = A[N,F] @ W[F,K]; A f16 [N][F], W f16 transposed [K][F].
// 128x128 tile, 4 waves, BK=32, single-term f16 MFMA.

__global__ __launch_bounds__(256) void gemm_mfma(const unsigned short* __restrict__ Af,
                                                 const unsigned short* __restrict__ Bt,
                                                 unsigned short* __restrict__ featb,
                                                 float* __restrict__ el,
                                                 float* __restrict__ er,
                                                 const float* __restrict__ al,
                                                 const float* __restrict__ ar,
                                                 int N, int F, int K) {
    __shared__ unsigned short As[128][40];  // [row m][k], 40 = 32 + 8 pad
    __shared__ unsigned short Bs[128][40];  // [col n][k]
    int tid = threadIdx.x;
    int lane = tid & 63, w = tid >> 6;
    int wr = (w >> 1) * 64, wc = (w & 1) * 64;
    int lr = lane & 15, lq = lane >> 4;
    int m0 = blockIdx.y * 128, n0 = blockIdx.x * 128;
    f32x4 acc[4][4] = {};

    for (int k0 = 0; k0 < F; k0 += 32) {
        __syncthreads();
        // stage A: 512 slots = 128 rows x 4 chunks (8 f16 = 16 B)
#pragma unroll
        for (int i = 0; i < 2; ++i) {
            int slot = i * 256 + tid;
            int r = slot >> 2, cc = slot & 3;
            uint4 v = make_uint4(0u, 0u, 0u, 0u);
            int gr = m0 + r;
            if (gr < N) v = *(const uint4*)&Af[(size_t)gr * F + k0 + cc * 8];
            *(uint4*)&As[r][cc * 8] = v;
        }
        // stage B
#pragma unroll
        for (int i = 0; i < 2; ++i) {
            int slot = i * 256 + tid;
            int r = slot >> 2, cc = slot & 3;
            uint4 bv = *(const uint4*)&Bt[(size_t)(n0 + r) * F + k0 + cc * 8];
            *(uint4*)&Bs[r][cc * 8] = bv;
        }
        __syncthreads();

        v8h af[4], bf[4];
#pragma unroll
        for (int mt = 0; mt < 4; ++mt)
            af[mt] = *(const v8h*)&As[wr + mt * 16 + lr][lq * 8];
#pragma unroll
        for (int nt = 0; nt < 4; ++nt)
            bf[nt] = *(const v8h*)&Bs[wc + nt * 16 + lr][lq * 8];
#pragma unroll
        for (int mt = 0; mt < 4; ++mt)
#pragma unroll
            for (int nt = 0; nt < 4; ++nt)
                acc[mt][nt] = __builtin_amdgcn_mfma_f32_16x16x32_f16(af[mt], bf[nt], acc[mt][nt], 0, 0, 0);
    }

    // ---- fused epilogue: el/er + bf16 featb ----
    int h = (n0 + wc) >> 6;  // head (D=64)
    float alw[4], arw[4];
#pragma unroll
    for (int nt = 0; nt < 4; ++nt) {
        int d = nt * 16 + lr;
        alw[nt] = al[h * 64 + d];
        arw[nt] = ar[h * 64 + d];
    }
#pragma unroll
    for (int mt = 0; mt < 4; ++mt) {
#pragma unroll
        for (int r = 0; r < 4; ++r) {
            float se = 0.f, sr = 0.f;
#pragma unroll
            for (int nt = 0; nt < 4; ++nt) {
                float v = acc[mt][nt][r];
                se += v * alw[nt];
                sr += v * arw[nt];
            }
#pragma unroll
            for (int o = 8; o >= 1; o >>= 1) {
                se += __shfl_xor(se, o);
                sr += __shfl_xor(sr, o);
            }
            int row = m0 + wr + mt * 16 + lq * 4 + r;
            if (lr == 0 && row < N) {
                el[(size_t)row * 4 + h] = se;
                er[(size_t)row * 4 + h] = sr;
            }
        }
    }
#pragma unroll
    for (int mt = 0; mt < 4; ++mt) {
#pragma unroll
        for (int nt = 0; nt < 4; ++nt) {
            int col = n0 + wc + nt * 16 + lr;
#pragma unroll
            for (int r = 0; r < 4; ++r) {
                int row = m0 + wr + mt * 16 + lq * 4 + r;
                if (row < N) featb[(size_t)row * K + col] = bf16_rne(acc[mt][nt][r]);
            }
        }
    }
}

// ---------------- fp32 GEMM (layer 2, K=16) fused with el/er + bf16 ------

__global__ __launch_bounds__(256) void gemm_kernel(const unsigned short* __restrict__ Af,
                                                   const float* __restrict__ W,
                                                   const float* __restrict__ al2,
                                                   const float* __restrict__ ar2,
                                                   float* __restrict__ el,
                                                   float* __restrict__ er,
                                                   unsigned short* __restrict__ featb,
                                                   int N, int F, int K) {
    __shared__ __align__(16) float As2[16][68];
    __shared__ __align__(16) float Ws2[16][64];
    int tid = threadIdx.x;
    int tx = tid & 15, ty = tid >> 4;
    int r0 = blockIdx.y * 64;
    int arow = tid >> 2, akq = tid & 3;
    int wk = tid >> 4, wcq = tid & 15;
    float acc[4][4] = {};

    for (int k0 = 0; k0 < F; k0 += 16) {
        float4 av = make_float4(0.f, 0.f, 0.f, 0.f);
        int gr = r0 + arow;
        if (gr < N) {
            size_t base = (size_t)gr * F + k0 + akq * 4;
            uint2 vh = *(const uint2*)&Af[base];
            av.x = f16_to_f32((unsigned short)(vh.x & 0xffffu));
            av.y = f16_to_f32((unsigned short)(vh.x >> 16));
            av.z = f16_to_f32((unsigned short)(vh.y & 0xffffu));
            av.w = f16_to_f32((unsigned short)(vh.y >> 16));
        }
        float4 wv = make_float4(0.f, 0.f, 0.f, 0.f);
        int gc = wcq * 4;
        if (gc < K) wv = *(const float4*)&W[(size_t)(k0 + wk) * K + gc];
        __syncthreads();
        As2[akq * 4 + 0][arow] = av.x;
        As2[akq * 4 + 1][arow] = av.y;
        As2[akq * 4 + 2][arow] = av.z;
        As2[akq * 4 + 3][arow] = av.w;
        *(float4*)&Ws2[wk][wcq * 4] = wv;
        __syncthreads();
#pragma unroll
        for (int k = 0; k < 16; ++k) {
            float4 a = *(const float4*)&As2[k][ty * 4];
            float4 wv2 = *(const float4*)&Ws2[k][tx * 4];
            acc[0][0] += a.x * wv2.x; acc[0][1] += a.x * wv2.y; acc[0][2] += a.x * wv2.z; acc[0][3] += a.x * wv2.w;
            acc[1][0] += a.y * wv2.x; acc[1][1] += a.y * wv2.y; acc[1][2] += a.y * wv2.z; acc[1][3] += a.y * wv2.w;
            acc[2][0] += a.z * wv2.x; acc[2][1] += a.z * wv2.y; acc[2][2] += a.z * wv2.z; acc[2][3] += a.z * wv2.w;
            acc[3][0] += a.w * wv2.x; acc[3][1] += a.w * wv2.y; acc[3][2] += a.w * wv2.z; acc[3][3] += a.w * wv2.w;
        }
    }
    float alv[4] = {0.f, 0.f, 0.f, 0.f}, arv[4] = {0.f, 0.f, 0.f, 0.f};
    if (tx < 4) {
#pragma unroll
        for (int c = 0; c < 4; ++c) {
            alv[c] = al2[tx * 4 + c];
            arv[c] = ar2[tx * 4 + c];
        }
    }
#pragma unroll
    for (int i = 0; i < 4; ++i) {
        int gr = r0 + ty * 4 + i;
        float pe = 0.f, pr = 0.f;
        if (tx < 4) {
#pragma unroll
            for (int c = 0; c < 4; ++c) {
                pe += acc[i][c] * alv[c];
                pr += acc[i][c] * arv[c];
            }
        }
        pe += __shfl_xor(pe, 1); pr += __shfl_xor(pr, 1);
        pe += __shfl_xor(pe, 2); pr += __shfl_xor(pr, 2);
        if (tx == 0 && gr < N) {
            el[gr] = pe;
            er[gr] = pr;
        }
        if (tx < 4 && gr < N) {
            ushort4 o4 = make_ushort4(bf16_rne(acc[i][0]), bf16_rne(acc[i][1]),
                                      bf16_rne(acc[i][2]), bf16_rne(acc[i][3]));
            *(ushort4*)&featb[(size_t)gr * 16 + tx * 4] = o4;
        }
    }
}

// ---------------- agg for H=4, D=64: wave-per-node ----------------
// Output written as a single f16 array (next layer's GEMM A operand).

template <int CAP, int U>
__global__ __launch_bounds__(256) void agg4_kernel(const unsigned short* __restrict__ featb,
                                                   const float* __restrict__ el,
                                                   const float* __restrict__ er,
                                                   const float* __restrict__ bias,
                                                   const int* __restrict__ off,
                                                   const int* __restrict__ csr,
                                                   unsigned short* __restrict__ outh, int N) {
    __shared__ float s_alpha[4][4][CAP];  // [wave][head][edge]
    __shared__ int s_src[4][CAP];
    int w = threadIdx.x >> 6;
    int lane = threadIdx.x & 63;
    int n = blockIdx.x * 4 + w;
    if (n >= N) return;
    int begin = off[n];
    int deg = off[n + 1] - begin;
    float4 ern = *(const float4*)&er[(size_t)n * 4];

    float m0 = -INFINITY, m1 = -INFINITY, m2 = -INFINITY, m3 = -INFINITY;
    float s0 = 0.f, s1 = 0.f, s2 = 0.f, s3 = 0.f;

    if (deg <= 64) {
        bool act = lane < deg;
        int s = 0;
        float e0 = -INFINITY, e1 = -INFINITY, e2 = -INFINITY, e3 = -INFINITY;
        if (act) {
            s = csr[begin + lane];
            float4 e = *(const float4*)&el[(size_t)s * 4];
            e0 = e.x + ern.x; e1 = e.y + ern.y; e2 = e.z + ern.z; e3 = e.w + ern.w;
            e0 = e0 > 0.f ? e0 : NEG_SLOPE * e0;
            e1 = e1 > 0.f ? e1 : NEG_SLOPE * e1;
            e2 = e2 > 0.f ? e2 : NEG_SLOPE * e2;
            e3 = e3 > 0.f ? e3 : NEG_SLOPE * e3;
        }
        m0 = e0; m1 = e1; m2 = e2; m3 = e3;
#pragma unroll
        for (int o = 32; o >= 1; o >>= 1) {
            m0 = fmaxf(m0, __shfl_xor(m0, o));
            m1 = fmaxf(m1, __shfl_xor(m1, o));
            m2 = fmaxf(m2, __shfl_xor(m2, o));
            m3 = fmaxf(m3, __shfl_xor(m3, o));
        }
        if (act) {
            s0 = __expf(e0 - m0); s1 = __expf(e1 - m1);
            s2 = __expf(e2 - m2); s3 = __expf(e3 - m3);
            s_src[w][lane] = s;
            s_alpha[w][0][lane] = s0;
            s_alpha[w][1][lane] = s1;
            s_alpha[w][2][lane] = s2;
            s_alpha[w][3][lane] = s3;
        }
#pragma unroll
        for (int o = 32; o >= 1; o >>= 1) {
            s0 += __shfl_xor(s0, o); s1 += __shfl_xor(s1, o);
            s2 += __shfl_xor(s2, o); s3 += __shfl_xor(s3, o);
        }
    } else {
        for (int i = lane; i < deg; i += 64) {
            int s = csr[begin + i];
            float4 e = *(const float4*)&el[(size_t)s * 4];
            float e0 = e.x + ern.x, e1 = e.y + ern.y, e2 = e.z + ern.z, e3 = e.w + ern.w;
            e0 = e0 > 0.f ? e0 : NEG_SLOPE * e0;
            e1 = e1 > 0.f ? e1 : NEG_SLOPE * e1;
            e2 = e2 > 0.f ? e2 : NEG_SLOPE * e2;
            e3 = e3 > 0.f ? e3 : NEG_SLOPE * e3;
            if (i < CAP) {
                s_src[w][i] = s;
                s_alpha[w][0][i] = e0; s_alpha[w][1][i] = e1;
                s_alpha[w][2][i] = e2; s_alpha[w][3][i] = e3;
            }
            m0 = fmaxf(m0, e0); m1 = fmaxf(m1, e1);
            m2 = fmaxf(m2, e2); m3 = fmaxf(m3, e3);
        }
#pragma unroll
        for (int o = 32; o >= 1; o >>= 1) {
            m0 = fmaxf(m0, __shfl_xor(m0, o));
            m1 = fmaxf(m1, __shfl_xor(m1, o));
            m2 = fmaxf(m2, __shfl_xor(m2, o));
            m3 = fmaxf(m3, __shfl_xor(m3, o));
        }
        for (int i = lane; i < deg; i += 64) {
            float e0, e1, e2, e3;
            if (i < CAP) {
                e0 = s_alpha[w][0][i]; e1 = s_alpha[w][1][i];
                e2 = s_alpha[w][2][i]; e3 = s_alpha[w][3][i];
            } else {
                int s = csr[begin + i];
                float4 e = *(const float4*)&el[(size_t)s * 4];
                e0 = e.x + ern.x; e1 = e.y + ern.y; e2 = e.z + ern.z; e3 = e.w + ern.w;
                e0 = e0 > 0.f ? e0 : NEG_SLOPE * e0;
                e1 = e1 > 0.f ? e1 : NEG_SLOPE * e1;
                e2 = e2 > 0.f ? e2 : NEG_SLOPE * e2;
                e3 = e3 > 0.f ? e3 : NEG_SLOPE * e3;
            }
            e0 = __expf(e0 - m0); e1 = __expf(e1 - m1);
            e2 = __expf(e2 - m2); e3 = __expf(e3 - m3);
            if (i < CAP) {
                s_alpha[w][0][i] = e0; s_alpha[w][1][i] = e1;
                s_alpha[w][2][i] = e2; s_alpha[w][3][i] = e3;
            }
            s0 += e0; s1 += e1; s2 += e2; s3 += e3;
        }
#pragma unroll
        for (int o = 32; o >= 1; o >>= 1) {
            s0 += __shfl_xor(s0, o); s1 += __shfl_xor(s1, o);
            s2 += __shfl_xor(s2, o); s3 += __shfl_xor(s3, o);
        }
    }

    float inv0 = deg > 0 ? 1.f / s0 : 0.f;
    float inv1 = deg > 0 ? 1.f / s1 : 0.f;
    float inv2 = deg > 0 ? 1.f / s2 : 0.f;
    float inv3 = deg > 0 ? 1.f / s3 : 0.f;

    int hsel = lane >> 5;
    int dcap = deg < CAP ? deg : CAP;
    const unsigned int* frow = (const unsigned int*)featb;
    float a0 = 0.f, a1 = 0.f, a2 = 0.f, a3 = 0.f;
    int j = 0;
    for (; j + U <= dcap; j += U) {
        int s[U];
        unsigned int f0[U], f1[U];
        float aA[U], aB[U];
#pragma unroll
        for (int u = 0; u < U; ++u) s[u] = s_src[w][j + u];
#pragma unroll
        for (int u = 0; u < U; ++u) {
            const unsigned int* rp = frow + (size_t)s[u] * 128;
            f0[u] = rp[lane];
            f1[u] = rp[64 + lane];
        }
#pragma unroll
        for (int u = 0; u < U; ++u) {
            aA[u] = s_alpha[w][hsel][j + u];
            aB[u] = s_alpha[w][2 + hsel][j + u];
        }
#pragma unroll
        for (int u = 0; u < U; ++u) {
            a0 += aA[u] * __uint_as_float(f0[u] << 16);
            a1 += aA[u] * __uint_as_float(f0[u] & 0xffff0000u);
            a2 += aB[u] * __uint_as_float(f1[u] << 16);
            a3 += aB[u] * __uint_as_float(f1[u] & 0xffff0000u);
        }
    }
    for (; j < dcap; ++j) {
        int s = s_src[w][j];
        const unsigned int* rp = frow + (size_t)s * 128;
        unsigned int f0v = rp[lane], f1v = rp[64 + lane];
        float aA = s_alpha[w][hsel][j], aB = s_alpha[w][2 + hsel][j];
        a0 += aA * __uint_as_float(f0v << 16);
        a1 += aA * __uint_as_float(f0v & 0xffff0000u);
        a2 += aB * __uint_as_float(f1v << 16);
        a3 += aB * __uint_as_float(f1v & 0xffff0000u);
    }
    for (int i = CAP; i < deg; ++i) {
        int s = csr[begin + i];
        float4 e = *(const float4*)&el[(size_t)s * 4];
        float e0 = e.x + ern.x, e1 = e.y + ern.y, e2 = e.z + ern.z, e3 = e.w + ern.w;
        e0 = e0 > 0.f ? e0 : NEG_SLOPE * e0;
        e1 = e1 > 0.f ? e1 : NEG_SLOPE * e1;
        e2 = e2 > 0.f ? e2 : NEG_SLOPE * e2;
        e3 = e3 > 0.f ? e3 : NEG_SLOPE * e3;
        float x0 = __expf(e0 - m0), x1 = __expf(e1 - m1);
        float x2 = __expf(e2 - m2), x3 = __expf(e3 - m3);
        float aA = hsel ? x1 : x0, aB = hsel ? x3 : x2;
        const unsigned int* rp = frow + (size_t)s * 128;
        unsigned int f0v = rp[lane], f1v = rp[64 + lane];
        a0 += aA * __uint_as_float(f0v << 16);
        a1 += aA * __uint_as_float(f0v & 0xffff0000u);
        a2 += aB * __uint_as_float(f1v << 16);
        a3 += aB * __uint_as_float(f1v & 0xffff0000u);
    }
    float invA = hsel ? inv1 : inv0;
    float invB = hsel ? inv3 : inv2;
    float o00 = a0 * invA + bias[2 * lane];
    float o01 = a1 * invA + bias[2 * lane + 1];
    float o10 = a2 * invB + bias[128 + 2 * lane];
    float o11 = a3 * invB + bias[128 + 2 * lane + 1];
    unsigned int* oph = (unsigned int*)outh;
    oph[(size_t)n * 128 + lane] = (unsigned int)f16_bits(o00) | ((unsigned int)f16_bits(o01) << 16);
    oph[(size_t)n * 128 + 64 + lane] = (unsigned int)f16_bits(o10) | ((unsigned int)f16_bits(o11) << 16);
}

// ---------------- agg for H=1, D=16 (layer 2): 4 nodes/block --------------

template <int CAP>
__global__ __launch_bounds__(256) void agg16_kernel(const unsigned short* __restrict__ featb,
                                                    const float* __restrict__ el,
                                                    const float* __restrict__ er,
                                                    const float* __restrict__ bias,
                                                    const int* __restrict__ off,
                                                    const int* __restrict__ csr,
                                                    float* __restrict__ out, int N) {
    __shared__ float s_alpha[4][CAP];
    __shared__ int s_src[4][CAP];
    int w = threadIdx.x >> 6;
    int lane = threadIdx.x & 63;
    int n = blockIdx.x * 4 + w;
    if (n >= N) return;
    int begin = off[n];
    int deg = off[n + 1] - begin;
    float ern = er[n];

    float m = -INFINITY, ssum = 0.f;
    if (deg <= 64) {
        bool act = lane < deg;
        int s = 0;
        float e = -INFINITY;
        if (act) {
            s = csr[begin + lane];
            e = el[s] + ern;
            e = e > 0.f ? e : NEG_SLOPE * e;
        }
        m = e;
#pragma unroll
        for (int o = 32; o >= 1; o >>= 1) m = fmaxf(m, __shfl_xor(m, o));
        float x = 0.f;
        if (act) {
            x = __expf(e - m);
            s_src[w][lane] = s;
            s_alpha[w][lane] = x;
        }
        ssum = x;
#pragma unroll
        for (int o = 32; o >= 1; o >>= 1) ssum += __shfl_xor(ssum, o);
    } else {
        for (int i = lane; i < deg; i += 64) {
            int s = csr[begin + i];
            float e = el[s] + ern;
            e = e > 0.f ? e : NEG_SLOPE * e;
            if (i < CAP) { s_src[w][i] = s; s_alpha[w][i] = e; }
            m = fmaxf(m, e);
        }
#pragma unroll
        for (int o = 32; o >= 1; o >>= 1) m = fmaxf(m, __shfl_xor(m, o));
        for (int i = lane; i < deg; i += 64) {
            float e;
            if (i < CAP) e = s_alpha[w][i];
            else {
                int s = csr[begin + i];
                e = el[s] + ern;
                e = e > 0.f ? e : NEG_SLOPE * e;
            }
            float x = __expf(e - m);
            if (i < CAP) s_alpha[w][i] = x;
            ssum += x;
        }
#pragma unroll
        for (int o = 32; o >= 1; o >>= 1) ssum += __shfl_xor(ssum, o);
    }
    float inv = deg > 0 ? 1.f / ssum : 0.f;

    int slot = lane >> 3, p = lane & 7;
    int dcap = deg < CAP ? deg : CAP;
    const unsigned int* frow = (const unsigned int*)featb;
    float ax = 0.f, ay = 0.f;
    for (int j = slot; j < dcap; j += 8) {
        int s = s_src[w][j];
        float a = s_alpha[w][j];
        unsigned int f = frow[(size_t)s * 8 + p];
        ax += a * __uint_as_float(f << 16);
        ay += a * __uint_as_float(f & 0xffff0000u);
    }
    for (int i = CAP + slot; i < deg; i += 8) {
        int s = csr[begin + i];
        float e = el[s] + ern;
        e = e > 0.f ? e : NEG_SLOPE * e;
        float x = __expf(e - m);
        unsigned int f = frow[(size_t)s * 8 + p];
        ax += x * __uint_as_float(f << 16);
        ay += x * __uint_as_float(f & 0xffff0000u);
    }
#pragma unroll
    for (int o = 8; o < 64; o <<= 1) {
        ax += __shfl_xor(ax, o);
        ay += __shfl_xor(ay, o);
    }
    if (lane < 8) {
        float2 o2 = make_float2(ax * inv + bias[2 * p], ay * inv + bias[2 * p + 1]);
        *(float2*)&out[(size_t)n * 16 + 2 * p] = o2;
    }
}

// ---------------- launch ----------------

extern "C" void kernel_launch(void* const* d_in, const int* in_sizes, int n_in,
                              void* d_out, int out_size, void* d_ws, size_t ws_size,
                              hipStream_t stream) {
    const float* inputs = (const float*)d_in[0];
    const float* W0 = (const float*)d_in[1];
    const float* al0 = (const float*)d_in[2];
    const float* ar0 = (const float*)d_in[3];
    const float* b0 = (const float*)d_in[4];
    const float* W1 = (const float*)d_in[5];
    const float* al1 = (const float*)d_in[6];
    const float* ar1 = (const float*)d_in[7];
    const float* b1 = (const float*)d_in[8];
    const float* W2 = (const float*)d_in[9];
    const float* al2 = (const float*)d_in[10];
    const float* ar2 = (const float*)d_in[11];
    const float* b2 = (const float*)d_in[12];
    const int* src = (const int*)d_in[13];
    const int* dst = (const int*)d_in[14];

    const int IN_DIM = 128;
    const int N = in_sizes[0] / IN_DIM;  // 50000
    const int E = in_sizes[13];          // 800000
    float* out = (float*)d_out;

    char* base = (char*)d_ws;
    size_t o = 0;
    auto carve = [&](size_t bytes) -> void* {
        void* p = base + o;
        o += (bytes + 255) & ~(size_t)255;
        return p;
    };
    int* off = (int*)carve((size_t)(N + 1) * sizeof(int));
    int* cursor = (int*)carve((size_t)N * sizeof(int));
    int* chunkSum = (int*)carve(64 * sizeof(int));
    int* chunkOff = (int*)carve(64 * sizeof(int));
    int* csr = (int*)carve((size_t)E * sizeof(int));
    float* el = (float*)carve((size_t)N * 4 * sizeof(float));
    float* er = (float*)carve((size_t)N * 4 * sizeof(float));
    unsigned short* featb = (unsigned short*)carve((size_t)N * 256 * sizeof(unsigned short));
    unsigned short* a0f = (unsigned short*)carve((size_t)N * 128 * sizeof(unsigned short));
    unsigned short* hbf = (unsigned short*)carve((size_t)N * 256 * sizeof(unsigned short));
    unsigned short* wt0 = (unsigned short*)carve((size_t)128 * 256 * sizeof(unsigned short));
    unsigned short* wt1 = (unsigned short*)carve((size_t)256 * 256 * sizeof(unsigned short));

    // ---- CSR build ----
    hipMemsetAsync(off, 0, (size_t)(N + 1) * sizeof(int), stream);
    int egrid = (E + 255) / 256;
    count_deg<<<egrid, 256, 0, stream>>>(dst, off, E);
    int nchunks = (N + 2047) / 2048;
    scan_chunk<<<nchunks, 256, 0, stream>>>(off, chunkSum, N);
    scan_tail<<<1, 64, 0, stream>>>(chunkSum, chunkOff, nchunks, off, N, E);
    add_chunk_off<<<(N + 255) / 256, 256, 0, stream>>>(off, cursor, chunkOff, N);
    scatter_edges<<<egrid, 256, 0, stream>>>(src, dst, cursor, csr, E);

    // ---- W + A prep (f16 casts) ----
    wcvt<<<(128 * 256 + 255) / 256, 256, 0, stream>>>(W0, wt0, 128, 256);
    wcvt<<<(256 * 256 + 255) / 256, 256, 0, stream>>>(W1, wt1, 256, 256);
    acvt<<<(N * 32 + 255) / 256, 256, 0, stream>>>(inputs, a0f, N * 32);

    // ---- Layer 0: 128 -> 4x64 (f16 MFMA, fused elr) ----
    {
        dim3 grid(256 / 128, (N + 127) / 128);
        gemm_mfma<<<grid, 256, 0, stream>>>(a0f, wt0, featb, el, er, al0, ar0, N, 128, 256);
        agg4_kernel<64, 8><<<(N + 3) / 4, 256, 0, stream>>>(featb, el, er, b0, off, csr, hbf, N);
    }
    // ---- Layer 1: 256 -> 4x64 (f16 MFMA, fused elr) ----
    {
        dim3 grid(256 / 128, (N + 127) / 128);
        gemm_mfma<<<grid, 256, 0, stream>>>(hbf, wt1, featb, el, er, al1, ar1, N, 256, 256);
        agg4_kernel<64, 8><<<(N + 3) / 4, 256, 0, stream>>>(featb, el, er, b1, off, csr, hbf, N);
    }
    // ---- Layer 2: 256 -> 1x16 (fp32 GEMM from f16 A, fused elr) ----
    {
        dim3 grid(1, (N + 63) / 64);
        gemm_kernel<<<grid, 256, 0, stream>>>(hbf, W2, al2, ar2, el, er, featb, N, 256, 16);
        agg16_kernel<64><<<(N + 3) / 4, 256, 0, stream>>>(featb, el, er, b2, off, csr, out, N);
    }
}

// Round 11
// 433.160 us; speedup vs baseline: 1.2444x; 1.0295x over previous
//
#include <hip/hip_runtime.h>
#include <hip/hip_bf16.h>
#include <math.h>

// ---------------------------------------------------------------------------
// GAT 3-layer forward.
// R11: agg4 phase-3 restructured to ONE dwordx2 load per edge per lane
// (lane owns 4 consecutive cols, head = lane>>4) instead of two dword loads
// -> half the vmem instructions/slots for the same bytes. Alpha via padded
// LDS multi-broadcast (s_alpha[..][65], banks h+j: conflict-free).
// Everything else identical to R10 (f16 single-term MFMA GEMM, fused elr,
// bf16 featb gather operand, f16 inter-layer activations).
// ---------------------------------------------------------------------------

#define NEG_SLOPE 0.2f

typedef __attribute__((ext_vector_type(8))) _Float16 v8h;  // 8 f16 in 4 VGPRs
typedef __attribute__((ext_vector_type(4))) float f32x4;

// ---------------- CSR build ----------------

__global__ __launch_bounds__(256) void count_deg(const int* __restrict__ dst,
                                                 int* __restrict__ deg, int E) {
    int e = blockIdx.x * 256 + threadIdx.x;
    if (e < E) atomicAdd(&deg[dst[e]], 1);
}

__global__ __launch_bounds__(256) void scan_chunk(int* __restrict__ off,
                                                  int* __restrict__ chunkSum, int N) {
    __shared__ int sdata[256];
    int tid = threadIdx.x;
    int base = blockIdx.x * 2048 + tid * 8;
    int v[8];
    int tsum = 0;
#pragma unroll
    for (int j = 0; j < 8; ++j) {
        int idx = base + j;
        v[j] = (idx < N) ? off[idx] : 0;
        tsum += v[j];
    }
    sdata[tid] = tsum;
    __syncthreads();
    for (int o = 1; o < 256; o <<= 1) {
        int t = (tid >= o) ? sdata[tid - o] : 0;
        __syncthreads();
        sdata[tid] += t;
        __syncthreads();
    }
    int run = sdata[tid] - tsum;
#pragma unroll
    for (int j = 0; j < 8; ++j) {
        int idx = base + j;
        if (idx < N) off[idx] = run;
        run += v[j];
    }
    if (tid == 255) chunkSum[blockIdx.x] = sdata[255];
}

__global__ void scan_tail(const int* __restrict__ chunkSum, int* __restrict__ chunkOff,
                          int nchunks, int* __restrict__ off, int N, int E) {
    if (threadIdx.x == 0 && blockIdx.x == 0) {
        int run = 0;
        for (int c = 0; c < nchunks; ++c) { chunkOff[c] = run; run += chunkSum[c]; }
        off[N] = E;
    }
}

__global__ __launch_bounds__(256) void add_chunk_off(int* __restrict__ off,
                                                     int* __restrict__ cursor,
                                                     const int* __restrict__ chunkOff, int N) {
    int i = blockIdx.x * 256 + threadIdx.x;
    if (i < N) {
        int v = off[i] + chunkOff[i >> 11];
        off[i] = v;
        cursor[i] = v;
    }
}

__global__ __launch_bounds__(256) void scatter_edges(const int* __restrict__ src,
                                                     const int* __restrict__ dst,
                                                     int* __restrict__ cursor,
                                                     int* __restrict__ csr, int E) {
    int e = blockIdx.x * 256 + threadIdx.x;
    if (e < E) {
        int d = dst[e];
        int pos = atomicAdd(&cursor[d], 1);
        csr[pos] = src[e];
    }
}

// ---------------- f16 helpers ----------------

__device__ __forceinline__ unsigned short bf16_rne(float x) {
    unsigned int u = __float_as_uint(x);
    return (unsigned short)((u + 0x7fffu + ((u >> 16) & 1u)) >> 16);
}

__device__ __forceinline__ unsigned short f16_bits(float x) {
    _Float16 h = (_Float16)x;
    union { _Float16 h; unsigned short u; } c;
    c.h = h;
    return c.u;
}

__device__ __forceinline__ float f16_to_f32(unsigned short u) {
    union { _Float16 h; unsigned short u; } c;
    c.u = u;
    return (float)c.h;
}

// W prep: W[F][K] fp32 -> Wt[K][F] f16 (transposed).
__global__ __launch_bounds__(256) void wcvt(const float* __restrict__ W,
                                            unsigned short* __restrict__ t,
                                            int F, int K) {
    int idx = blockIdx.x * 256 + threadIdx.x;
    if (idx >= F * K) return;
    int f = idx / K, k = idx % K;
    t[k * F + f] = f16_bits(W[idx]);
}

// A prep: fp32 stream -> f16, 4 elems/thread.
__global__ __launch_bounds__(256) void acvt(const float* __restrict__ A,
                                            unsigned short* __restrict__ h,
                                            int total4) {
    int i = blockIdx.x * 256 + threadIdx.x;
    if (i >= total4) return;
    float4 v = *(const float4*)&A[(size_t)i * 4];
    *(ushort4*)&h[(size_t)i * 4] = make_ushort4(f16_bits(v.x), f16_bits(v.y),
                                                f16_bits(v.z), f16_bits(v.w));
}

// ---------------- f16 MFMA GEMM fused with el/er + bf16 featb -------------

__global__ __launch_bounds__(256) void gemm_mfma(const unsigned short* __restrict__ Af,
                                                 const unsigned short* __restrict__ Bt,
                                                 unsigned short* __restrict__ featb,
                                                 float* __restrict__ el,
                                                 float* __restrict__ er,
                                                 const float* __restrict__ al,
                                                 const float* __restrict__ ar,
                                                 int N, int F, int K) {
    __shared__ unsigned short As[128][40];
    __shared__ unsigned short Bs[128][40];
    int tid = threadIdx.x;
    int lane = tid & 63, w = tid >> 6;
    int wr = (w >> 1) * 64, wc = (w & 1) * 64;
    int lr = lane & 15, lq = lane >> 4;
    int m0 = blockIdx.y * 128, n0 = blockIdx.x * 128;
    f32x4 acc[4][4] = {};

    for (int k0 = 0; k0 < F; k0 += 32) {
        __syncthreads();
#pragma unroll
        for (int i = 0; i < 2; ++i) {
            int slot = i * 256 + tid;
            int r = slot >> 2, cc = slot & 3;
            uint4 v = make_uint4(0u, 0u, 0u, 0u);
            int gr = m0 + r;
            if (gr < N) v = *(const uint4*)&Af[(size_t)gr * F + k0 + cc * 8];
            *(uint4*)&As[r][cc * 8] = v;
        }
#pragma unroll
        for (int i = 0; i < 2; ++i) {
            int slot = i * 256 + tid;
            int r = slot >> 2, cc = slot & 3;
            uint4 bv = *(const uint4*)&Bt[(size_t)(n0 + r) * F + k0 + cc * 8];
            *(uint4*)&Bs[r][cc * 8] = bv;
        }
        __syncthreads();

        v8h af[4], bf[4];
#pragma unroll
        for (int mt = 0; mt < 4; ++mt)
            af[mt] = *(const v8h*)&As[wr + mt * 16 + lr][lq * 8];
#pragma unroll
        for (int nt = 0; nt < 4; ++nt)
            bf[nt] = *(const v8h*)&Bs[wc + nt * 16 + lr][lq * 8];
#pragma unroll
        for (int mt = 0; mt < 4; ++mt)
#pragma unroll
            for (int nt = 0; nt < 4; ++nt)
                acc[mt][nt] = __builtin_amdgcn_mfma_f32_16x16x32_f16(af[mt], bf[nt], acc[mt][nt], 0, 0, 0);
    }

    int h = (n0 + wc) >> 6;
    float alw[4], arw[4];
#pragma unroll
    for (int nt = 0; nt < 4; ++nt) {
        int d = nt * 16 + lr;
        alw[nt] = al[h * 64 + d];
        arw[nt] = ar[h * 64 + d];
    }
#pragma unroll
    for (int mt = 0; mt < 4; ++mt) {
#pragma unroll
        for (int r = 0; r < 4; ++r) {
            float se = 0.f, sr = 0.f;
#pragma unroll
            for (int nt = 0; nt < 4; ++nt) {
                float v = acc[mt][nt][r];
                se += v * alw[nt];
                sr += v * arw[nt];
            }
#pragma unroll
            for (int o = 8; o >= 1; o >>= 1) {
                se += __shfl_xor(se, o);
                sr += __shfl_xor(sr, o);
            }
            int row = m0 + wr + mt * 16 + lq * 4 + r;
            if (lr == 0 && row < N) {
                el[(size_t)row * 4 + h] = se;
                er[(size_t)row * 4 + h] = sr;
            }
        }
    }
#pragma unroll
    for (int mt = 0; mt < 4; ++mt) {
#pragma unroll
        for (int nt = 0; nt < 4; ++nt) {
            int col = n0 + wc + nt * 16 + lr;
#pragma unroll
            for (int r = 0; r < 4; ++r) {
                int row = m0 + wr + mt * 16 + lq * 4 + r;
                if (row < N) featb[(size_t)row * K + col] = bf16_rne(acc[mt][nt][r]);
            }
        }
    }
}

// ---------------- fp32 GEMM (layer 2, K=16) fused with el/er + bf16 ------

__global__ __launch_bounds__(256) void gemm_kernel(const unsigned short* __restrict__ Af,
                                                   const float* __restrict__ W,
                                                   const float* __restrict__ al2,
                                                   const float* __restrict__ ar2,
                                                   float* __restrict__ el,
                                                   float* __restrict__ er,
                                                   unsigned short* __restrict__ featb,
                                                   int N, int F, int K) {
    __shared__ __align__(16) float As2[16][68];
    __shared__ __align__(16) float Ws2[16][64];
    int tid = threadIdx.x;
    int tx = tid & 15, ty = tid >> 4;
    int r0 = blockIdx.y * 64;
    int arow = tid >> 2, akq = tid & 3;
    int wk = tid >> 4, wcq = tid & 15;
    float acc[4][4] = {};

    for (int k0 = 0; k0 < F; k0 += 16) {
        float4 av = make_float4(0.f, 0.f, 0.f, 0.f);
        int gr = r0 + arow;
        if (gr < N) {
            size_t base = (size_t)gr * F + k0 + akq * 4;
            uint2 vh = *(const uint2*)&Af[base];
            av.x = f16_to_f32((unsigned short)(vh.x & 0xffffu));
            av.y = f16_to_f32((unsigned short)(vh.x >> 16));
            av.z = f16_to_f32((unsigned short)(vh.y & 0xffffu));
            av.w = f16_to_f32((unsigned short)(vh.y >> 16));
        }
        float4 wv = make_float4(0.f, 0.f, 0.f, 0.f);
        int gc = wcq * 4;
        if (gc < K) wv = *(const float4*)&W[(size_t)(k0 + wk) * K + gc];
        __syncthreads();
        As2[akq * 4 + 0][arow] = av.x;
        As2[akq * 4 + 1][arow] = av.y;
        As2[akq * 4 + 2][arow] = av.z;
        As2[akq * 4 + 3][arow] = av.w;
        *(float4*)&Ws2[wk][wcq * 4] = wv;
        __syncthreads();
#pragma unroll
        for (int k = 0; k < 16; ++k) {
            float4 a = *(const float4*)&As2[k][ty * 4];
            float4 wv2 = *(const float4*)&Ws2[k][tx * 4];
            acc[0][0] += a.x * wv2.x; acc[0][1] += a.x * wv2.y; acc[0][2] += a.x * wv2.z; acc[0][3] += a.x * wv2.w;
            acc[1][0] += a.y * wv2.x; acc[1][1] += a.y * wv2.y; acc[1][2] += a.y * wv2.z; acc[1][3] += a.y * wv2.w;
            acc[2][0] += a.z * wv2.x; acc[2][1] += a.z * wv2.y; acc[2][2] += a.z * wv2.z; acc[2][3] += a.z * wv2.w;
            acc[3][0] += a.w * wv2.x; acc[3][1] += a.w * wv2.y; acc[3][2] += a.w * wv2.z; acc[3][3] += a.w * wv2.w;
        }
    }
    float alv[4] = {0.f, 0.f, 0.f, 0.f}, arv[4] = {0.f, 0.f, 0.f, 0.f};
    if (tx < 4) {
#pragma unroll
        for (int c = 0; c < 4; ++c) {
            alv[c] = al2[tx * 4 + c];
            arv[c] = ar2[tx * 4 + c];
        }
    }
#pragma unroll
    for (int i = 0; i < 4; ++i) {
        int gr = r0 + ty * 4 + i;
        float pe = 0.f, pr = 0.f;
        if (tx < 4) {
#pragma unroll
            for (int c = 0; c < 4; ++c) {
                pe += acc[i][c] * alv[c];
                pr += acc[i][c] * arv[c];
            }
        }
        pe += __shfl_xor(pe, 1); pr += __shfl_xor(pr, 1);
        pe += __shfl_xor(pe, 2); pr += __shfl_xor(pr, 2);
        if (tx == 0 && gr < N) {
            el[gr] = pe;
            er[gr] = pr;
        }
        if (tx < 4 && gr < N) {
            ushort4 o4 = make_ushort4(bf16_rne(acc[i][0]), bf16_rne(acc[i][1]),
                                      bf16_rne(acc[i][2]), bf16_rne(acc[i][3]));
            *(ushort4*)&featb[(size_t)gr * 16 + tx * 4] = o4;
        }
    }
}

// ---------------- agg for H=4, D=64: wave-per-node, dwordx2 gather --------
// Phase 3: lane owns cols 4*lane..4*lane+3 (head = lane>>4); one uint2 load
// per edge per lane (512 B per wave in a single instruction). Alpha from
// padded LDS (stride 65 -> banks h+j, conflict-free 4-way broadcast).

template <int U>
__global__ __launch_bounds__(256) void agg4_kernel(const unsigned short* __restrict__ featb,
                                                   const float* __restrict__ el,
                                                   const float* __restrict__ er,
                                                   const float* __restrict__ bias,
                                                   const int* __restrict__ off,
                                                   const int* __restrict__ csr,
                                                   unsigned short* __restrict__ outh, int N) {
    constexpr int CAP = 64;
    __shared__ float s_alpha[4][4][65];  // [wave][head][edge], 65-pad
    __shared__ int s_src[4][CAP];
    int w = threadIdx.x >> 6;
    int lane = threadIdx.x & 63;
    int n = blockIdx.x * 4 + w;
    if (n >= N) return;
    int begin = off[n];
    int deg = off[n + 1] - begin;
    float4 ern = *(const float4*)&er[(size_t)n * 4];

    float m0 = -INFINITY, m1 = -INFINITY, m2 = -INFINITY, m3 = -INFINITY;
    float s0 = 0.f, s1 = 0.f, s2 = 0.f, s3 = 0.f;

    if (deg <= 64) {
        bool act = lane < deg;
        int s = 0;
        float e0 = -INFINITY, e1 = -INFINITY, e2 = -INFINITY, e3 = -INFINITY;
        if (act) {
            s = csr[begin + lane];
            float4 e = *(const float4*)&el[(size_t)s * 4];
            e0 = e.x + ern.x; e1 = e.y + ern.y; e2 = e.z + ern.z; e3 = e.w + ern.w;
            e0 = e0 > 0.f ? e0 : NEG_SLOPE * e0;
            e1 = e1 > 0.f ? e1 : NEG_SLOPE * e1;
            e2 = e2 > 0.f ? e2 : NEG_SLOPE * e2;
            e3 = e3 > 0.f ? e3 : NEG_SLOPE * e3;
        }
        m0 = e0; m1 = e1; m2 = e2; m3 = e3;
#pragma unroll
        for (int o = 32; o >= 1; o >>= 1) {
            m0 = fmaxf(m0, __shfl_xor(m0, o));
            m1 = fmaxf(m1, __shfl_xor(m1, o));
            m2 = fmaxf(m2, __shfl_xor(m2, o));
            m3 = fmaxf(m3, __shfl_xor(m3, o));
        }
        if (act) {
            s0 = __expf(e0 - m0); s1 = __expf(e1 - m1);
            s2 = __expf(e2 - m2); s3 = __expf(e3 - m3);
            s_src[w][lane] = s;
            s_alpha[w][0][lane] = s0;
            s_alpha[w][1][lane] = s1;
            s_alpha[w][2][lane] = s2;
            s_alpha[w][3][lane] = s3;
        }
#pragma unroll
        for (int o = 32; o >= 1; o >>= 1) {
            s0 += __shfl_xor(s0, o); s1 += __shfl_xor(s1, o);
            s2 += __shfl_xor(s2, o); s3 += __shfl_xor(s3, o);
        }
    } else {
        for (int i = lane; i < deg; i += 64) {
            int s = csr[begin + i];
            float4 e = *(const float4*)&el[(size_t)s * 4];
            float e0 = e.x + ern.x, e1 = e.y + ern.y, e2 = e.z + ern.z, e3 = e.w + ern.w;
            e0 = e0 > 0.f ? e0 : NEG_SLOPE * e0;
            e1 = e1 > 0.f ? e1 : NEG_SLOPE * e1;
            e2 = e2 > 0.f ? e2 : NEG_SLOPE * e2;
            e3 = e3 > 0.f ? e3 : NEG_SLOPE * e3;
            if (i < CAP) {
                s_src[w][i] = s;
                s_alpha[w][0][i] = e0; s_alpha[w][1][i] = e1;
                s_alpha[w][2][i] = e2; s_alpha[w][3][i] = e3;
            }
            m0 = fmaxf(m0, e0); m1 = fmaxf(m1, e1);
            m2 = fmaxf(m2, e2); m3 = fmaxf(m3, e3);
        }
#pragma unroll
        for (int o = 32; o >= 1; o >>= 1) {
            m0 = fmaxf(m0, __shfl_xor(m0, o));
            m1 = fmaxf(m1, __shfl_xor(m1, o));
            m2 = fmaxf(m2, __shfl_xor(m2, o));
            m3 = fmaxf(m3, __shfl_xor(m3, o));
        }
        for (int i = lane; i < deg; i += 64) {
            float e0, e1, e2, e3;
            if (i < CAP) {
                e0 = s_alpha[w][0][i]; e1 = s_alpha[w][1][i];
                e2 = s_alpha[w][2][i]; e3 = s_alpha[w][3][i];
            } else {
                int s = csr[begin + i];
                float4 e = *(const float4*)&el[(size_t)s * 4];
                e0 = e.x + ern.x; e1 = e.y + ern.y; e2 = e.z + ern.z; e3 = e.w + ern.w;
                e0 = e0 > 0.f ? e0 : NEG_SLOPE * e0;
                e1 = e1 > 0.f ? e1 : NEG_SLOPE * e1;
                e2 = e2 > 0.f ? e2 : NEG_SLOPE * e2;
                e3 = e3 > 0.f ? e3 : NEG_SLOPE * e3;
            }
            e0 = __expf(e0 - m0); e1 = __expf(e1 - m1);
            e2 = __expf(e2 - m2); e3 = __expf(e3 - m3);
            if (i < CAP) {
                s_alpha[w][0][i] = e0; s_alpha[w][1][i] = e1;
                s_alpha[w][2][i] = e2; s_alpha[w][3][i] = e3;
            }
            s0 += e0; s1 += e1; s2 += e2; s3 += e3;
        }
#pragma unroll
        for (int o = 32; o >= 1; o >>= 1) {
            s0 += __shfl_xor(s0, o); s1 += __shfl_xor(s1, o);
            s2 += __shfl_xor(s2, o); s3 += __shfl_xor(s3, o);
        }
    }

    float inv0 = deg > 0 ? 1.f / s0 : 0.f;
    float inv1 = deg > 0 ? 1.f / s1 : 0.f;
    float inv2 = deg > 0 ? 1.f / s2 : 0.f;
    float inv3 = deg > 0 ? 1.f / s3 : 0.f;

    // ---- phase 3: lane owns cols 4*lane..4*lane+3; head = lane>>4 ----
    int h = lane >> 4;
    float inv = h == 0 ? inv0 : (h == 1 ? inv1 : (h == 2 ? inv2 : inv3));
    float mh = h == 0 ? m0 : (h == 1 ? m1 : (h == 2 ? m2 : m3));
    const uint2* frow2 = (const uint2*)featb;  // row = 64 uint2 (256 bf16)
    float c0 = 0.f, c1 = 0.f, c2 = 0.f, c3 = 0.f;
    int dcap = deg < CAP ? deg : CAP;
    int j = 0;
    for (; j + U <= dcap; j += U) {
        int s[U];
        uint2 g[U];
        float a[U];
#pragma unroll
        for (int u = 0; u < U; ++u) s[u] = s_src[w][j + u];
#pragma unroll
        for (int u = 0; u < U; ++u) g[u] = frow2[(size_t)s[u] * 64 + lane];
#pragma unroll
        for (int u = 0; u < U; ++u) a[u] = s_alpha[w][h][j + u];
#pragma unroll
        for (int u = 0; u < U; ++u) {
            c0 += a[u] * __uint_as_float(g[u].x << 16);
            c1 += a[u] * __uint_as_float(g[u].x & 0xffff0000u);
            c2 += a[u] * __uint_as_float(g[u].y << 16);
            c3 += a[u] * __uint_as_float(g[u].y & 0xffff0000u);
        }
    }
    for (; j < dcap; ++j) {
        int s = s_src[w][j];
        uint2 g = frow2[(size_t)s * 64 + lane];
        float a = s_alpha[w][h][j];
        c0 += a * __uint_as_float(g.x << 16);
        c1 += a * __uint_as_float(g.x & 0xffff0000u);
        c2 += a * __uint_as_float(g.y << 16);
        c3 += a * __uint_as_float(g.y & 0xffff0000u);
    }
    // spill path deg > CAP: recompute alpha for this lane's head
    for (int i = CAP; i < deg; ++i) {
        int s = csr[begin + i];
        float4 e = *(const float4*)&el[(size_t)s * 4];
        float eh = h == 0 ? e.x + ern.x : (h == 1 ? e.y + ern.y : (h == 2 ? e.z + ern.z : e.w + ern.w));
        eh = eh > 0.f ? eh : NEG_SLOPE * eh;
        float a = __expf(eh - mh);
        uint2 g = frow2[(size_t)s * 64 + lane];
        c0 += a * __uint_as_float(g.x << 16);
        c1 += a * __uint_as_float(g.x & 0xffff0000u);
        c2 += a * __uint_as_float(g.y << 16);
        c3 += a * __uint_as_float(g.y & 0xffff0000u);
    }
    float4 b4 = *(const float4*)&bias[4 * lane];
    float o0 = c0 * inv + b4.x;
    float o1 = c1 * inv + b4.y;
    float o2 = c2 * inv + b4.z;
    float o3 = c3 * inv + b4.w;
    uint2 pack;
    pack.x = (unsigned int)f16_bits(o0) | ((unsigned int)f16_bits(o1) << 16);
    pack.y = (unsigned int)f16_bits(o2) | ((unsigned int)f16_bits(o3) << 16);
    ((uint2*)outh)[(size_t)n * 64 + lane] = pack;
}

// ---------------- agg for H=1, D=16 (layer 2): 4 nodes/block --------------

template <int CAP>
__global__ __launch_bounds__(256) void agg16_kernel(const unsigned short* __restrict__ featb,
                                                    const float* __restrict__ el,
                                                    const float* __restrict__ er,
                                                    const float* __restrict__ bias,
                                                    const int* __restrict__ off,
                                                    const int* __restrict__ csr,
                                                    float* __restrict__ out, int N) {
    __shared__ float s_alpha[4][CAP];
    __shared__ int s_src[4][CAP];
    int w = threadIdx.x >> 6;
    int lane = threadIdx.x & 63;
    int n = blockIdx.x * 4 + w;
    if (n >= N) return;
    int begin = off[n];
    int deg = off[n + 1] - begin;
    float ern = er[n];

    float m = -INFINITY, ssum = 0.f;
    if (deg <= 64) {
        bool act = lane < deg;
        int s = 0;
        float e = -INFINITY;
        if (act) {
            s = csr[begin + lane];
            e = el[s] + ern;
            e = e > 0.f ? e : NEG_SLOPE * e;
        }
        m = e;
#pragma unroll
        for (int o = 32; o >= 1; o >>= 1) m = fmaxf(m, __shfl_xor(m, o));
        float x = 0.f;
        if (act) {
            x = __expf(e - m);
            s_src[w][lane] = s;
            s_alpha[w][lane] = x;
        }
        ssum = x;
#pragma unroll
        for (int o = 32; o >= 1; o >>= 1) ssum += __shfl_xor(ssum, o);
    } else {
        for (int i = lane; i < deg; i += 64) {
            int s = csr[begin + i];
            float e = el[s] + ern;
            e = e > 0.f ? e : NEG_SLOPE * e;
            if (i < CAP) { s_src[w][i] = s; s_alpha[w][i] = e; }
            m = fmaxf(m, e);
        }
#pragma unroll
        for (int o = 32; o >= 1; o >>= 1) m = fmaxf(m, __shfl_xor(m, o));
        for (int i = lane; i < deg; i += 64) {
            float e;
            if (i < CAP) e = s_alpha[w][i];
            else {
                int s = csr[begin + i];
                e = el[s] + ern;
                e = e > 0.f ? e : NEG_SLOPE * e;
            }
            float x = __expf(e - m);
            if (i < CAP) s_alpha[w][i] = x;
            ssum += x;
        }
#pragma unroll
        for (int o = 32; o >= 1; o >>= 1) ssum += __shfl_xor(ssum, o);
    }
    float inv = deg > 0 ? 1.f / ssum : 0.f;

    int slot = lane >> 3, p = lane & 7;
    int dcap = deg < CAP ? deg : CAP;
    const unsigned int* frow = (const unsigned int*)featb;
    float ax = 0.f, ay = 0.f;
    for (int j = slot; j < dcap; j += 8) {
        int s = s_src[w][j];
        float a = s_alpha[w][j];
        unsigned int f = frow[(size_t)s * 8 + p];
        ax += a * __uint_as_float(f << 16);
        ay += a * __uint_as_float(f & 0xffff0000u);
    }
    for (int i = CAP + slot; i < deg; i += 8) {
        int s = csr[begin + i];
        float e = el[s] + ern;
        e = e > 0.f ? e : NEG_SLOPE * e;
        float x = __expf(e - m);
        unsigned int f = frow[(size_t)s * 8 + p];
        ax += x * __uint_as_float(f << 16);
        ay += x * __uint_as_float(f & 0xffff0000u);
    }
#pragma unroll
    for (int o = 8; o < 64; o <<= 1) {
        ax += __shfl_xor(ax, o);
        ay += __shfl_xor(ay, o);
    }
    if (lane < 8) {
        float2 o2 = make_float2(ax * inv + bias[2 * p], ay * inv + bias[2 * p + 1]);
        *(float2*)&out[(size_t)n * 16 + 2 * p] = o2;
    }
}

// ---------------- launch ----------------

extern "C" void kernel_launch(void* const* d_in, const int* in_sizes, int n_in,
                              void* d_out, int out_size, void* d_ws, size_t ws_size,
                              hipStream_t stream) {
    const float* inputs = (const float*)d_in[0];
    const float* W0 = (const float*)d_in[1];
    const float* al0 = (const float*)d_in[2];
    const float* ar0 = (const float*)d_in[3];
    const float* b0 = (const float*)d_in[4];
    const float* W1 = (const float*)d_in[5];
    const float* al1 = (const float*)d_in[6];
    const float* ar1 = (const float*)d_in[7];
    const float* b1 = (const float*)d_in[8];
    const float* W2 = (const float*)d_in[9];
    const float* al2 = (const float*)d_in[10];
    const float* ar2 = (const float*)d_in[11];
    const float* b2 = (const float*)d_in[12];
    const int* src = (const int*)d_in[13];
    const int* dst = (const int*)d_in[14];

    const int IN_DIM = 128;
    const int N = in_sizes[0] / IN_DIM;  // 50000
    const int E = in_sizes[13];          // 800000
    float* out = (float*)d_out;

    char* base = (char*)d_ws;
    size_t o = 0;
    auto carve = [&](size_t bytes) -> void* {
        void* p = base + o;
        o += (bytes + 255) & ~(size_t)255;
        return p;
    };
    int* off = (int*)carve((size_t)(N + 1) * sizeof(int));
    int* cursor = (int*)carve((size_t)N * sizeof(int));
    int* chunkSum = (int*)carve(64 * sizeof(int));
    int* chunkOff = (int*)carve(64 * sizeof(int));
    int* csr = (int*)carve((size_t)E * sizeof(int));
    float* el = (float*)carve((size_t)N * 4 * sizeof(float));
    float* er = (float*)carve((size_t)N * 4 * sizeof(float));
    unsigned short* featb = (unsigned short*)carve((size_t)N * 256 * sizeof(unsigned short));
    unsigned short* a0f = (unsigned short*)carve((size_t)N * 128 * sizeof(unsigned short));
    unsigned short* hbf = (unsigned short*)carve((size_t)N * 256 * sizeof(unsigned short));
    unsigned short* wt0 = (unsigned short*)carve((size_t)128 * 256 * sizeof(unsigned short));
    unsigned short* wt1 = (unsigned short*)carve((size_t)256 * 256 * sizeof(unsigned short));

    // ---- CSR build ----
    hipMemsetAsync(off, 0, (size_t)(N + 1) * sizeof(int), stream);
    int egrid = (E + 255) / 256;
    count_deg<<<egrid, 256, 0, stream>>>(dst, off, E);
    int nchunks = (N + 2047) / 2048;
    scan_chunk<<<nchunks, 256, 0, stream>>>(off, chunkSum, N);
    scan_tail<<<1, 64, 0, stream>>>(chunkSum, chunkOff, nchunks, off, N, E);
    add_chunk_off<<<(N + 255) / 256, 256, 0, stream>>>(off, cursor, chunkOff, N);
    scatter_edges<<<egrid, 256, 0, stream>>>(src, dst, cursor, csr, E);

    // ---- W + A prep (f16 casts) ----
    wcvt<<<(128 * 256 + 255) / 256, 256, 0, stream>>>(W0, wt0, 128, 256);
    wcvt<<<(256 * 256 + 255) / 256, 256, 0, stream>>>(W1, wt1, 256, 256);
    acvt<<<(N * 32 + 255) / 256, 256, 0, stream>>>(inputs, a0f, N * 32);

    // ---- Layer 0: 128 -> 4x64 (f16 MFMA, fused elr) ----
    {
        dim3 grid(256 / 128, (N + 127) / 128);
        gemm_mfma<<<grid, 256, 0, stream>>>(a0f, wt0, featb, el, er, al0, ar0, N, 128, 256);
        agg4_kernel<8><<<(N + 3) / 4, 256, 0, stream>>>(featb, el, er, b0, off, csr, hbf, N);
    }
    // ---- Layer 1: 256 -> 4x64 (f16 MFMA, fused elr) ----
    {
        dim3 grid(256 / 128, (N + 127) / 128);
        gemm_mfma<<<grid, 256, 0, stream>>>(hbf, wt1, featb, el, er, al1, ar1, N, 256, 256);
        agg4_kernel<8><<<(N + 3) / 4, 256, 0, stream>>>(featb, el, er, b1, off, csr, hbf, N);
    }
    // ---- Layer 2: 256 -> 1x16 (fp32 GEMM from f16 A, fused elr) ----
    {
        dim3 grid(1, (N + 63) / 64);
        gemm_kernel<<<grid, 256, 0, stream>>>(hbf, W2, al2, ar2, el, er, featb, N, 256, 16);
        agg16_kernel<64><<<(N + 3) / 4, 256, 0, stream>>>(featb, el, er, b2, off, csr, out, N);
    }
}